// Round 4
// baseline (808.258 us; speedup 1.0000x reference)
//
#include <hip/hip_runtime.h>
#include <math.h>

#define BSZ 4
#define LEN 2048
#define DM 1024
#define DI 2048
#define HD 64      // HEADDIM (p)
#define NH 32      // NHEADS
#define DS 128     // D_STATE (n)
#define CD 2304    // CONV_DIM
#define DP 4384    // D_IN_PROJ
#define NTOK (BSZ*LEN)   // 8192
#define QCH 128          // chunk length
#define NCH (LEN/QCH)    // 16 chunks
#define TOFF (DP-NH)     // 4352: dt raw cols in W_in

#define CONV_R 64
#define NRB (NTOK/CONV_R)
#define NPAD 4480        // W_in columns padded to 35*128
#define GLD 136          // Gs LDS leading dim (bf16 elems)

typedef unsigned short ushort_t;
typedef __bf16 bf16x8 __attribute__((ext_vector_type(8)));
typedef ushort_t us8 __attribute__((ext_vector_type(8)));
typedef float f32x4 __attribute__((ext_vector_type(4)));

__device__ __forceinline__ ushort_t f2bf(float f) {
    unsigned u = __float_as_uint(f);
    unsigned r = (u + 0x7FFFu + ((u >> 16) & 1u)) >> 16;
    return (ushort_t)r;
}
__device__ __forceinline__ float bf2f(ushort_t u) {
    return __uint_as_float(((unsigned)u) << 16);
}
__device__ __forceinline__ bf16x8 us2bf(us8 v) {
    union { us8 u; bf16x8 b; } x; x.u = v; return x.b;
}

__device__ __forceinline__ void gl_lds16(const void* g, void* l) {
    __builtin_amdgcn_global_load_lds(
        (const __attribute__((address_space(1))) void*)g,
        (__attribute__((address_space(3))) void*)l, 16, 0, 0);
}

// ---------------------------------------------------------------------------
// fp32 -> bf16 elementwise (hidden). 4 elems/thread.
// ---------------------------------------------------------------------------
__global__ __launch_bounds__(256) void cvt_bf16(
    const float* __restrict__ A, ushort_t* __restrict__ Ab)
{
    size_t i = ((size_t)blockIdx.x * 256 + threadIdx.x) * 4;
    float4 v = *(const float4*)(A + i);
    ushort_t o[4] = { f2bf(v.x), f2bf(v.y), f2bf(v.z), f2bf(v.w) };
    *(uint2*)(Ab + i) = *(uint2*)o;
}

// ---------------------------------------------------------------------------
// W[k][n] fp32 (ld=ldw) -> Wt[n][k] bf16 (ld=K), zero-pad for n >= N.
// ---------------------------------------------------------------------------
__global__ __launch_bounds__(256) void transpose_cvt(
    const float* __restrict__ W, ushort_t* __restrict__ Wt,
    int K, int N, int ldw)
{
    __shared__ float T[32][33];
    const int n0 = blockIdx.x * 32;
    const int k0 = blockIdx.y * 32;
    const int tid = threadIdx.x;
    #pragma unroll
    for (int l = 0; l < 4; l++) {
        int idx = tid + l * 256;
        int ki = idx >> 5, nj = idx & 31;
        int n = n0 + nj;
        T[ki][nj] = (n < N) ? W[(size_t)(k0 + ki) * ldw + n] : 0.f;
    }
    __syncthreads();
    #pragma unroll
    for (int l = 0; l < 4; l++) {
        int idx = tid + l * 256;
        int nj = idx >> 5, ki = idx & 31;
        Wt[(size_t)(n0 + nj) * K + k0 + ki] = f2bf(T[ki][nj]);
    }
}

// ---------------------------------------------------------------------------
// bf16 MFMA GEMM (B^T form): C[m][n] = sum_k A[m][k] * Bt[n][k].
// 128x128 tile, BK=32, m97 structure. OB: bf16 output else fp32.
// ---------------------------------------------------------------------------
template <bool OB>
__global__ __launch_bounds__(256) void gemm_bf16(
    const ushort_t* __restrict__ A, const ushort_t* __restrict__ Bt,
    void* __restrict__ Cp, int K, int lda, int ldb, int ldc, int nmax)
{
    __shared__ __align__(16) ushort_t As[128 * 32];
    __shared__ __align__(16) ushort_t Bs[128 * 32];
    const int tid = threadIdx.x;
    const int n0 = blockIdx.x * 128;
    const int m0 = blockIdx.y * 128;
    const int lane = tid & 63;
    const int w = tid >> 6;
    const int wm = w >> 1, wn = w & 1;
    const int lm = lane & 15, quad = lane >> 4;

    const int srow = tid >> 2;
    const int skq = (tid & 3) * 8;
    const ushort_t* ga0 = A + (size_t)(m0 + srow) * lda + skq;
    const ushort_t* ga1 = A + (size_t)(m0 + 64 + srow) * lda + skq;
    const ushort_t* gb0 = Bt + (size_t)(n0 + srow) * ldb + skq;
    const ushort_t* gb1 = Bt + (size_t)(n0 + 64 + srow) * ldb + skq;
    ushort_t* la0 = &As[srow * 32 + skq];
    ushort_t* la1 = &As[(64 + srow) * 32 + skq];
    ushort_t* lb0 = &Bs[srow * 32 + skq];
    ushort_t* lb1 = &Bs[(64 + srow) * 32 + skq];

    f32x4 acc[4][4];
    #pragma unroll
    for (int i = 0; i < 4; i++)
        #pragma unroll
        for (int j = 0; j < 4; j++) acc[i][j] = (f32x4){0.f, 0.f, 0.f, 0.f};

    for (int k0 = 0; k0 < K; k0 += 32) {
        gl_lds16(ga0, la0);
        gl_lds16(ga1, la1);
        gl_lds16(gb0, lb0);
        gl_lds16(gb1, lb1);
        ga0 += 32; ga1 += 32; gb0 += 32; gb1 += 32;
        __syncthreads();
        bf16x8 af[4], bfr[4];
        #pragma unroll
        for (int i = 0; i < 4; i++)
            af[i] = *(const bf16x8*)&As[(wm * 64 + i * 16 + lm) * 32 + quad * 8];
        #pragma unroll
        for (int j = 0; j < 4; j++)
            bfr[j] = *(const bf16x8*)&Bs[(wn * 64 + j * 16 + lm) * 32 + quad * 8];
        #pragma unroll
        for (int i = 0; i < 4; i++)
            #pragma unroll
            for (int j = 0; j < 4; j++)
                acc[i][j] = __builtin_amdgcn_mfma_f32_16x16x32_bf16(af[i], bfr[j], acc[i][j], 0, 0, 0);
        __syncthreads();
    }

    #pragma unroll
    for (int i = 0; i < 4; i++) {
        int row = m0 + wm * 64 + i * 16 + quad * 4;
        #pragma unroll
        for (int j = 0; j < 4; j++) {
            int col = n0 + wn * 64 + j * 16 + lm;
            if (col < nmax) {
                #pragma unroll
                for (int r = 0; r < 4; r++) {
                    if (OB)
                        ((ushort_t*)Cp)[(size_t)(row + r) * ldc + col] = f2bf(acc[i][j][r]);
                    else
                        ((float*)Cp)[(size_t)(row + r) * ldc + col] = acc[i][j][r];
                }
            }
        }
    }
}

// ---------------------------------------------------------------------------
// Depthwise causal conv (w=4) + bias + SiLU. Reads compact fp32 xbcf
// [NTOK][CD]; emits bf16 operand caches: xT[DI][NTOK], Bn[NTOK][DS],
// BT[DS][NTOK], Cn[NTOK][DS]. Not in-place -> no halo needed.
// ---------------------------------------------------------------------------
__global__ __launch_bounds__(256) void conv_silu_bf16(
    const float* __restrict__ xbcf, const float* __restrict__ cw,
    const float* __restrict__ cb, ushort_t* __restrict__ xT,
    ushort_t* __restrict__ Bn, ushort_t* __restrict__ BT,
    ushort_t* __restrict__ Cn)
{
    const int c = blockIdx.x * 256 + threadIdx.x;   // 0..2303
    const int rb = blockIdx.y;
    const int row0 = rb * CONV_R;
    const float w0 = cw[c*4+0], w1 = cw[c*4+1], w2 = cw[c*4+2], w3 = cw[c*4+3];
    const float bias = cb[c];
    float h0 = 0.f, h1 = 0.f, h2 = 0.f;
    if ((row0 & (LEN - 1)) != 0) {
        h0 = xbcf[(size_t)(row0 - 3) * CD + c];
        h1 = xbcf[(size_t)(row0 - 2) * CD + c];
        h2 = xbcf[(size_t)(row0 - 1) * CD + c];
    }
    const float* p = xbcf + (size_t)row0 * CD + c;
    for (int r = 0; r < CONV_R; r++) {
        int row = row0 + r;
        float xin = *p;
        float a = bias + w0*h0 + w1*h1 + w2*h2 + w3*xin;
        ushort_t bv = f2bf(a / (1.f + __expf(-a)));
        if (c < DI) {
            xT[(size_t)c * NTOK + row] = bv;
        } else if (c < DI + DS) {
            int n = c - DI;
            BT[(size_t)n * NTOK + row] = bv;
            Bn[(size_t)row * DS + n] = bv;
        } else {
            int n = c - DI - DS;
            Cn[(size_t)row * DS + n] = bv;
        }
        h0 = h1; h1 = h2; h2 = xin;
        p += CD;
    }
}

// ---------------------------------------------------------------------------
// dt in FULL fp32 straight from hidden @ W_in[:, TOFF:] (exp-amplified path).
// ---------------------------------------------------------------------------
__global__ __launch_bounds__(256) void dt_proc_fp32(
    const float* __restrict__ hidden, const float* __restrict__ W_in,
    const float* __restrict__ dt_bias, const float* __restrict__ A_log,
    float* __restrict__ dtv, float* __restrict__ ldA)
{
    const int h = threadIdx.x & 31;
    const int tt = threadIdx.x >> 5;
    const int t = blockIdx.x * 8 + tt;
    const float* hr = hidden + (size_t)t * DM;
    const float* wc = W_in + TOFF + h;
    float acc = 0.f;
    #pragma unroll 4
    for (int k = 0; k < DM; k++) acc += hr[k] * wc[(size_t)k * DP];
    float v = acc + dt_bias[h];
    float sp = (v > 20.f) ? v : log1pf(expf(v));
    int idx = t * NH + h;
    dtv[idx] = sp;
    ldA[idx] = -sp * expf(A_log[h]);
}

// ---------------------------------------------------------------------------
// Phase 1 (MFMA): per (b,h,chunk): S[p][n] = sum_s (coef_s*x[s,p]) * B[s,n].
// M=p=64, N=n=128, K=s=128. Fragments loaded directly from global (xT, BT).
// ---------------------------------------------------------------------------
__global__ __launch_bounds__(256) void phase1_mfma(
    const ushort_t* __restrict__ xT, const ushort_t* __restrict__ BT,
    const float* __restrict__ dtv, const float* __restrict__ ldA,
    float* __restrict__ S, float* __restrict__ csum)
{
    const int blk = blockIdx.x;
    const int chunk = blk % NCH;
    const int bh = blk / NCH;
    const int h = bh % NH;
    const int b = bh / NH;
    const int tid = threadIdx.x;
    const size_t rowbase = (size_t)b * LEN + (size_t)chunk * QCH;

    __shared__ float lcp[QCH];
    __shared__ float coef[QCH];
    if (tid < QCH) lcp[tid] = ldA[(rowbase + tid) * NH + h];
    __syncthreads();
    for (int off = 1; off < QCH; off <<= 1) {
        float v = 0.f;
        if (tid < QCH && tid >= off) v = lcp[tid - off];
        __syncthreads();
        if (tid < QCH) lcp[tid] += v;
        __syncthreads();
    }
    if (tid < QCH) coef[tid] = __expf(lcp[QCH - 1] - lcp[tid]) * dtv[(rowbase + tid) * NH + h];
    if (tid == 0) csum[blk] = lcp[QCH - 1];
    __syncthreads();

    const int w = tid >> 6, lane = tid & 63;
    const int lm = lane & 15, quad = lane >> 4;
    const int nw0 = w * 32;

    f32x4 acc[4][2];
    #pragma unroll
    for (int i = 0; i < 4; i++)
        #pragma unroll
        for (int j = 0; j < 2; j++) acc[i][j] = (f32x4){0.f, 0.f, 0.f, 0.f};

    #pragma unroll
    for (int ks = 0; ks < 4; ks++) {
        const int k0 = ks * 32 + quad * 8;
        bf16x8 a[4];
        #pragma unroll
        for (int mi = 0; mi < 4; mi++)
            a[mi] = *(const bf16x8*)&xT[(size_t)(h * HD + mi * 16 + lm) * NTOK + rowbase + k0];
        float cf[8];
        #pragma unroll
        for (int j = 0; j < 8; j++) cf[j] = coef[k0 + j];
        #pragma unroll
        for (int ni = 0; ni < 2; ni++) {
            us8 raw = *(const us8*)&BT[(size_t)(nw0 + ni * 16 + lm) * NTOK + rowbase + k0];
            us8 sb;
            #pragma unroll
            for (int j = 0; j < 8; j++) sb[j] = f2bf(bf2f(raw[j]) * cf[j]);
            bf16x8 bfr = us2bf(sb);
            #pragma unroll
            for (int mi = 0; mi < 4; mi++)
                acc[mi][ni] = __builtin_amdgcn_mfma_f32_16x16x32_bf16(a[mi], bfr, acc[mi][ni], 0, 0, 0);
        }
    }
    float* Sb = S + (size_t)blk * (HD * DS);
    #pragma unroll
    for (int mi = 0; mi < 4; mi++)
        #pragma unroll
        for (int ni = 0; ni < 2; ni++)
            #pragma unroll
            for (int r = 0; r < 4; r++)
                Sb[(size_t)(mi * 16 + quad * 4 + r) * DS + nw0 + ni * 16 + lm] = acc[mi][ni][r];
}

// ---------------------------------------------------------------------------
// Phase 2: cross-chunk recurrence. Overwrites S[c] with h_start(chunk c).
// ---------------------------------------------------------------------------
__global__ __launch_bounds__(256) void phase2(
    float* __restrict__ S, const float* __restrict__ csum)
{
    const int bh = blockIdx.x;
    const int tid = threadIdx.x;
    float run[32];
    #pragma unroll
    for (int i = 0; i < 32; i++) run[i] = 0.f;
    for (int c = 0; c < NCH; c++) {
        float P = __expf(csum[bh * NCH + c]);
        float* Sb = S + (size_t)(bh * NCH + c) * (HD * DS);
        #pragma unroll
        for (int i = 0; i < 32; i++) {
            int idx = tid + i * 256;
            float s = Sb[idx];
            Sb[idx] = run[i];
            run[i] = P * run[i] + s;
        }
    }
}

// ---------------------------------------------------------------------------
// Phase 3 (MFMA): per (b,h,chunk):
//  Step A: G^T[s][t] = sum_n B[s,n]*C[t,n] via MFMA (natural layouts), then
//          weight w(t,s)=exp(lcp_t-lcp_s)*dt_s*(s<=t) and store bf16 G[t][s]
//          to LDS in A-operand layout.
//  Step B: Y[t][p] = sum_{k<128} G[t,s]*xT[p,s]  +  sum_{k>=128} Chat[t,n]*hs[p,n]
//          — one fused K=256 MFMA contraction. Epilogue adds D*x and
//          overwrites the block's own (dead) S region with y[t*HD+p].
// ---------------------------------------------------------------------------
__global__ __launch_bounds__(256) void phase3_mfma(
    const ushort_t* __restrict__ xT, const ushort_t* __restrict__ Bn,
    const ushort_t* __restrict__ Cn, const float* __restrict__ dtv,
    const float* __restrict__ ldA, const float* __restrict__ Dvec,
    float* __restrict__ S)
{
    const int tid = threadIdx.x;
    const int blk = blockIdx.x;
    const int chunk = blk % NCH;
    const int bh = blk / NCH;
    const int h = bh % NH;
    const int b = bh / NH;
    const size_t rowbase = (size_t)b * LEN + (size_t)chunk * QCH;

    __shared__ float lcp[QCH];
    __shared__ float dts[QCH];
    __shared__ __align__(16) ushort_t Gs[QCH * GLD];

    if (tid < QCH) {
        lcp[tid] = ldA[(rowbase + tid) * NH + h];
        dts[tid] = dtv[(rowbase + tid) * NH + h];
    }
    __syncthreads();
    for (int off = 1; off < QCH; off <<= 1) {
        float v = 0.f;
        if (tid < QCH && tid >= off) v = lcp[tid - off];
        __syncthreads();
        if (tid < QCH) lcp[tid] += v;
        __syncthreads();
    }

    const int w = tid >> 6, lane = tid & 63;
    const int lm = lane & 15, quad = lane >> 4;

    // ---- Step A: G^T (s-range per wave: sw0..sw0+31) ----
    {
        const int sw0 = w * 32;
        f32x4 acc[2][8];
        #pragma unroll
        for (int si = 0; si < 2; si++)
            #pragma unroll
            for (int ti = 0; ti < 8; ti++) acc[si][ti] = (f32x4){0.f, 0.f, 0.f, 0.f};

        #pragma unroll
        for (int ks = 0; ks < 4; ks++) {
            const int k0 = ks * 32 + quad * 8;
            bf16x8 a0 = *(const bf16x8*)&Bn[(rowbase + sw0 + lm) * DS + k0];
            bf16x8 a1 = *(const bf16x8*)&Bn[(rowbase + sw0 + 16 + lm) * DS + k0];
            #pragma unroll
            for (int ti = 0; ti < 8; ti++) {
                bf16x8 cf = *(const bf16x8*)&Cn[(rowbase + ti * 16 + lm) * DS + k0];
                acc[0][ti] = __builtin_amdgcn_mfma_f32_16x16x32_bf16(a0, cf, acc[0][ti], 0, 0, 0);
                acc[1][ti] = __builtin_amdgcn_mfma_f32_16x16x32_bf16(a1, cf, acc[1][ti], 0, 0, 0);
            }
        }
        // weight + mask + store bf16 G[t][s] to LDS
        #pragma unroll
        for (int si = 0; si < 2; si++)
            #pragma unroll
            for (int ti = 0; ti < 8; ti++) {
                int t = ti * 16 + lm;
                float lt = lcp[t];
                ushort_t pk[4];
                #pragma unroll
                for (int r = 0; r < 4; r++) {
                    int s = sw0 + si * 16 + quad * 4 + r;
                    float wv = (s <= t) ? (__expf(lt - lcp[s]) * dts[s]) : 0.f;
                    pk[r] = f2bf(acc[si][ti][r] * wv);
                }
                *(ushort4*)&Gs[t * GLD + sw0 + si * 16 + quad * 4] = *(ushort4*)pk;
            }
    }
    __syncthreads();

    // ---- Step B: fused Y = G@X + Chat@hs^T (K = 128 + 128) ----
    const int tw0 = w * 32;
    const float* hsb = S + (size_t)blk * (HD * DS);
    f32x4 acc2[2][4];
    #pragma unroll
    for (int ti = 0; ti < 2; ti++)
        #pragma unroll
        for (int pi = 0; pi < 4; pi++) acc2[ti][pi] = (f32x4){0.f, 0.f, 0.f, 0.f};

    #pragma unroll
    for (int ks = 0; ks < 8; ks++) {
        bf16x8 a[2], bb[4];
        if (ks < 4) {
            const int k0 = ks * 32 + quad * 8;
            a[0] = *(const bf16x8*)&Gs[(tw0 + lm) * GLD + k0];
            a[1] = *(const bf16x8*)&Gs[(tw0 + 16 + lm) * GLD + k0];
            #pragma unroll
            for (int pi = 0; pi < 4; pi++)
                bb[pi] = *(const bf16x8*)&xT[(size_t)(h * HD + pi * 16 + lm) * NTOK + rowbase + k0];
        } else {
            const int k0 = (ks - 4) * 32 + quad * 8;
            #pragma unroll
            for (int ti = 0; ti < 2; ti++) {
                int t = tw0 + ti * 16 + lm;
                float sc = __expf(lcp[t]);
                us8 raw = *(const us8*)&Cn[(rowbase + t) * DS + k0];
                us8 sb;
                #pragma unroll
                for (int j = 0; j < 8; j++) sb[j] = f2bf(bf2f(raw[j]) * sc);
                a[ti] = us2bf(sb);
            }
            #pragma unroll
            for (int pi = 0; pi < 4; pi++) {
                const float* hp = &hsb[(size_t)(pi * 16 + lm) * DS + k0];
                float4 h0 = *(const float4*)hp;
                float4 h1 = *(const float4*)(hp + 4);
                us8 sb;
                sb[0] = f2bf(h0.x); sb[1] = f2bf(h0.y); sb[2] = f2bf(h0.z); sb[3] = f2bf(h0.w);
                sb[4] = f2bf(h1.x); sb[5] = f2bf(h1.y); sb[6] = f2bf(h1.z); sb[7] = f2bf(h1.w);
                bb[pi] = us2bf(sb);
            }
        }
        #pragma unroll
        for (int ti = 0; ti < 2; ti++)
            #pragma unroll
            for (int pi = 0; pi < 4; pi++)
                acc2[ti][pi] = __builtin_amdgcn_mfma_f32_16x16x32_bf16(a[ti], bb[pi], acc2[ti][pi], 0, 0, 0);
    }

    __syncthreads();   // all hs reads complete before overwrite
    const float Dh = Dvec[h];
    float* yb = S + (size_t)blk * (HD * DS);
    #pragma unroll
    for (int ti = 0; ti < 2; ti++)
        #pragma unroll
        for (int pi = 0; pi < 4; pi++) {
            int tb = tw0 + ti * 16 + quad * 4;
            ushort4 xv = *(const ushort4*)&xT[(size_t)(h * HD + pi * 16 + lm) * NTOK + rowbase + tb];
            const ushort_t* xe = (const ushort_t*)&xv;
            #pragma unroll
            for (int r = 0; r < 4; r++) {
                float y = acc2[ti][pi][r] + Dh * bf2f(xe[r]);
                yb[(size_t)(tb + r) * HD + pi * 16 + lm] = y;
            }
        }
}

// ---------------------------------------------------------------------------
// Gate (y * silu(z)) + RMSNorm over DI. z from bf16; writes bf16 y_norm
// [NTOK][DI] (GEMM2's A operand).
// ---------------------------------------------------------------------------
__global__ __launch_bounds__(256) void gate_rms(
    const ushort_t* __restrict__ zb, const float* __restrict__ Sy,
    const float* __restrict__ nw, ushort_t* __restrict__ ynb)
{
    const int row = blockIdx.x;
    const int tid = threadIdx.x;
    const int b = row >> 11;
    const int l = row & (LEN - 1);
    const int chunk = l >> 7;
    const int t = l & (QCH - 1);
    const ushort_t* zr = zb + (size_t)row * DI;
    float g[8];
    float ss = 0.f;
    #pragma unroll
    for (int i = 0; i < 8; i++) {
        int c = tid + i * 256;
        int h = c >> 6;
        int p = c & 63;
        float y = Sy[((size_t)((b * NH + h) * NCH + chunk)) * (HD * DS) + t * HD + p];
        float z = bf2f(zr[c]);
        float sg = z / (1.f + __expf(-z));
        float v = y * sg;
        g[i] = v;
        ss += v * v;
    }
    #pragma unroll
    for (int off = 32; off > 0; off >>= 1) ss += __shfl_down(ss, off, 64);
    __shared__ float red[4];
    if ((tid & 63) == 0) red[tid >> 6] = ss;
    __syncthreads();
    float tot = red[0] + red[1] + red[2] + red[3];
    float r = rsqrtf(tot * (1.f / DI) + 1e-5f);
    #pragma unroll
    for (int i = 0; i < 8; i++) {
        int c = tid + i * 256;
        ynb[(size_t)row * DI + c] = f2bf(g[i] * r * nw[c]);
    }
}

// ---------------------------------------------------------------------------
extern "C" void kernel_launch(void* const* d_in, const int* in_sizes, int n_in,
                              void* d_out, int out_size, void* d_ws, size_t ws_size,
                              hipStream_t stream)
{
    const float* hidden  = (const float*)d_in[0];
    const float* W_in    = (const float*)d_in[1];
    const float* conv_w  = (const float*)d_in[2];
    const float* conv_b  = (const float*)d_in[3];
    const float* dt_bias = (const float*)d_in[4];
    const float* A_log   = (const float*)d_in[5];
    const float* Dv      = (const float*)d_in[6];
    const float* norm_w  = (const float*)d_in[7];
    const float* W_out   = (const float*)d_in[8];
    float* out = (float*)d_out;

    char* ws = (char*)d_ws;
    size_t o = 0;
    ushort_t* zb  = (ushort_t*)(ws + o); o += (size_t)NTOK * DI * 2;               // 33.6 MB
    float* xbcf   = (float*)(ws + o);    o += (size_t)NTOK * CD * 4;               // 75.5 MB
    float* S      = (float*)(ws + o);    o += (size_t)BSZ * NH * NCH * HD * DS * 4;// 67.1 MB
    ushort_t* xT  = (ushort_t*)(ws + o); o += (size_t)DI * NTOK * 2;               // 33.6 MB
    ushort_t* Bn  = (ushort_t*)(ws + o); o += (size_t)NTOK * DS * 2;               // 2.1 MB
    ushort_t* BT  = (ushort_t*)(ws + o); o += (size_t)DS * NTOK * 2;               // 2.1 MB
    ushort_t* Cn  = (ushort_t*)(ws + o); o += (size_t)NTOK * DS * 2;               // 2.1 MB
    float* dtv    = (float*)(ws + o);    o += (size_t)NTOK * NH * 4;               // 1.05 MB
    float* ldA    = (float*)(ws + o);    o += (size_t)NTOK * NH * 4;               // 1.05 MB
    float* csum   = (float*)(ws + o);    o += (size_t)BSZ * NH * NCH * 4;          // 8 KB
    // total ~218.1 MB
    // Aliases (dead-region reuse):
    ushort_t* Ah  = (ushort_t*)S;                                   // pre-phase1
    ushort_t* W1t = (ushort_t*)((char*)S + (size_t)NTOK * DM * 2);  // pre-phase1
    ushort_t* Wot = (ushort_t*)S;                                   // post-gate_rms
    ushort_t* ynb = (ushort_t*)xbcf;                                // post-conv

    // 1) bf16 conversions for GEMM1
    cvt_bf16<<<(NTOK * DM) / 1024, 256, 0, stream>>>(hidden, Ah);
    transpose_cvt<<<dim3(NPAD / 32, DM / 32), 256, 0, stream>>>(W_in, W1t, DM, DP, DP);
    // 2) GEMM1 split: z part (bf16 out), xBC part (fp32 out)
    gemm_bf16<true><<<dim3(DI / 128, NTOK / 128), 256, 0, stream>>>(
        Ah, W1t, zb, DM, DM, DM, DI, DI);
    gemm_bf16<false><<<dim3(19, NTOK / 128), 256, 0, stream>>>(
        Ah, W1t + (size_t)DI * DM, xbcf, DM, DM, DM, CD, CD);
    // 3) conv + SiLU -> bf16 operand caches
    conv_silu_bf16<<<dim3(CD / 256, NRB), 256, 0, stream>>>(
        xbcf, conv_w, conv_b, xT, Bn, BT, Cn);
    // 4) dt in fp32
    dt_proc_fp32<<<NTOK / 8, 256, 0, stream>>>(hidden, W_in, dt_bias, A_log, dtv, ldA);
    // 5) chunk states (MFMA) — overwrites Ah/W1t alias region (dead)
    phase1_mfma<<<BSZ * NH * NCH, 256, 0, stream>>>(xT, BT, dtv, ldA, S, csum);
    // 6) cross-chunk recurrence
    phase2<<<BSZ * NH, 256, 0, stream>>>(S, csum);
    // 7) per-chunk outputs (MFMA) — overwrites S with y
    phase3_mfma<<<BSZ * NH * NCH, 256, 0, stream>>>(xT, Bn, Cn, dtv, ldA, Dv, S);
    // 8) gate + RMSNorm -> bf16 y_norm (into xbcf alias)
    gate_rms<<<NTOK, 256, 0, stream>>>(zb, S, norm_w, ynb);
    // 9) W_out transpose (S dead), then out = y_norm @ W_out
    transpose_cvt<<<dim3(DM / 32, DI / 32), 256, 0, stream>>>(W_out, Wot, DI, DM, DM);
    gemm_bf16<false><<<dim3(DM / 128, NTOK / 128), 256, 0, stream>>>(
        ynb, Wot, out, DI, DI, DI, DM, DM);
}

// Round 5
// 620.737 us; speedup vs baseline: 1.3021x; 1.3021x over previous
//
#include <hip/hip_runtime.h>
#include <math.h>

#define BSZ 4
#define LEN 2048
#define DM 1024
#define DI 2048
#define HD 64      // HEADDIM (p)
#define NH 32      // NHEADS
#define DS 128     // D_STATE (n)
#define CD 2304    // CONV_DIM
#define DP 4384    // D_IN_PROJ
#define NTOK (BSZ*LEN)   // 8192
#define QCH 128          // chunk length
#define NCH (LEN/QCH)    // 16 chunks
#define TOFF (DP-NH)     // 4352: dt raw cols in W_in

#define CONV_R 64
#define NRB (NTOK/CONV_R)
#define NPAD 4480        // W_in columns padded to 35*128
#define GLD 136          // Gs LDS leading dim (bf16 elems)

typedef unsigned short ushort_t;
typedef __bf16 bf16x8 __attribute__((ext_vector_type(8)));
typedef ushort_t us8 __attribute__((ext_vector_type(8)));
typedef float f32x4 __attribute__((ext_vector_type(4)));

__device__ __forceinline__ ushort_t f2bf(float f) {
    unsigned u = __float_as_uint(f);
    unsigned r = (u + 0x7FFFu + ((u >> 16) & 1u)) >> 16;
    return (ushort_t)r;
}
__device__ __forceinline__ float bf2f(ushort_t u) {
    return __uint_as_float(((unsigned)u) << 16);
}
__device__ __forceinline__ bf16x8 us2bf(us8 v) {
    union { us8 u; bf16x8 b; } x; x.u = v; return x.b;
}

__device__ __forceinline__ void gl_lds16(const void* g, void* l) {
    __builtin_amdgcn_global_load_lds(
        (const __attribute__((address_space(1))) void*)g,
        (__attribute__((address_space(3))) void*)l, 16, 0, 0);
}

// ---------------------------------------------------------------------------
// fp32 -> bf16 elementwise (hidden). 4 elems/thread.
// ---------------------------------------------------------------------------
__global__ __launch_bounds__(256) void cvt_bf16(
    const float* __restrict__ A, ushort_t* __restrict__ Ab)
{
    size_t i = ((size_t)blockIdx.x * 256 + threadIdx.x) * 4;
    float4 v = *(const float4*)(A + i);
    ushort_t o[4] = { f2bf(v.x), f2bf(v.y), f2bf(v.z), f2bf(v.w) };
    *(uint2*)(Ab + i) = *(uint2*)o;
}

// ---------------------------------------------------------------------------
// W[k][n] fp32 (ld=ldw) -> Wt[n][k] bf16 (ld=K), zero-pad for n >= N.
// ---------------------------------------------------------------------------
__global__ __launch_bounds__(256) void transpose_cvt(
    const float* __restrict__ W, ushort_t* __restrict__ Wt,
    int K, int N, int ldw)
{
    __shared__ float T[32][33];
    const int n0 = blockIdx.x * 32;
    const int k0 = blockIdx.y * 32;
    const int tid = threadIdx.x;
    #pragma unroll
    for (int l = 0; l < 4; l++) {
        int idx = tid + l * 256;
        int ki = idx >> 5, nj = idx & 31;
        int n = n0 + nj;
        T[ki][nj] = (n < N) ? W[(size_t)(k0 + ki) * ldw + n] : 0.f;
    }
    __syncthreads();
    #pragma unroll
    for (int l = 0; l < 4; l++) {
        int idx = tid + l * 256;
        int nj = idx >> 5, ki = idx & 31;
        Wt[(size_t)(n0 + nj) * K + k0 + ki] = f2bf(T[ki][nj]);
    }
}

// ---------------------------------------------------------------------------
// bf16 MFMA GEMM (B^T form): C[m][n] = sum_k A[m][k] * Bt[n][k].
// 128x128 tile, BK=32, m97 structure. OB: bf16 output else fp32.
// ---------------------------------------------------------------------------
template <bool OB>
__global__ __launch_bounds__(256) void gemm_bf16(
    const ushort_t* __restrict__ A, const ushort_t* __restrict__ Bt,
    void* __restrict__ Cp, int K, int lda, int ldb, int ldc, int nmax)
{
    __shared__ __align__(16) ushort_t As[128 * 32];
    __shared__ __align__(16) ushort_t Bs[128 * 32];
    const int tid = threadIdx.x;
    const int n0 = blockIdx.x * 128;
    const int m0 = blockIdx.y * 128;
    const int lane = tid & 63;
    const int w = tid >> 6;
    const int wm = w >> 1, wn = w & 1;
    const int lm = lane & 15, quad = lane >> 4;

    const int srow = tid >> 2;
    const int skq = (tid & 3) * 8;
    const ushort_t* ga0 = A + (size_t)(m0 + srow) * lda + skq;
    const ushort_t* ga1 = A + (size_t)(m0 + 64 + srow) * lda + skq;
    const ushort_t* gb0 = Bt + (size_t)(n0 + srow) * ldb + skq;
    const ushort_t* gb1 = Bt + (size_t)(n0 + 64 + srow) * ldb + skq;
    ushort_t* la0 = &As[srow * 32 + skq];
    ushort_t* la1 = &As[(64 + srow) * 32 + skq];
    ushort_t* lb0 = &Bs[srow * 32 + skq];
    ushort_t* lb1 = &Bs[(64 + srow) * 32 + skq];

    f32x4 acc[4][4];
    #pragma unroll
    for (int i = 0; i < 4; i++)
        #pragma unroll
        for (int j = 0; j < 4; j++) acc[i][j] = (f32x4){0.f, 0.f, 0.f, 0.f};

    for (int k0 = 0; k0 < K; k0 += 32) {
        gl_lds16(ga0, la0);
        gl_lds16(ga1, la1);
        gl_lds16(gb0, lb0);
        gl_lds16(gb1, lb1);
        ga0 += 32; ga1 += 32; gb0 += 32; gb1 += 32;
        __syncthreads();
        bf16x8 af[4], bfr[4];
        #pragma unroll
        for (int i = 0; i < 4; i++)
            af[i] = *(const bf16x8*)&As[(wm * 64 + i * 16 + lm) * 32 + quad * 8];
        #pragma unroll
        for (int j = 0; j < 4; j++)
            bfr[j] = *(const bf16x8*)&Bs[(wn * 64 + j * 16 + lm) * 32 + quad * 8];
        #pragma unroll
        for (int i = 0; i < 4; i++)
            #pragma unroll
            for (int j = 0; j < 4; j++)
                acc[i][j] = __builtin_amdgcn_mfma_f32_16x16x32_bf16(af[i], bfr[j], acc[i][j], 0, 0, 0);
        __syncthreads();
    }

    #pragma unroll
    for (int i = 0; i < 4; i++) {
        int row = m0 + wm * 64 + i * 16 + quad * 4;
        #pragma unroll
        for (int j = 0; j < 4; j++) {
            int col = n0 + wn * 64 + j * 16 + lm;
            if (col < nmax) {
                #pragma unroll
                for (int r = 0; r < 4; r++) {
                    if (OB)
                        ((ushort_t*)Cp)[(size_t)(row + r) * ldc + col] = f2bf(acc[i][j][r]);
                    else
                        ((float*)Cp)[(size_t)(row + r) * ldc + col] = acc[i][j][r];
                }
            }
        }
    }
}

// ---------------------------------------------------------------------------
// Depthwise causal conv (w=4) + bias + SiLU -> bf16 operand caches.
// Reads compact fp32 xbcf [NTOK][CD] (coalesced: lane = channel).
// Transposed outputs (xT[c][row], BT[n][row]) go through an LDS tile so each
// store is 16B covering 8 consecutive rows -> full cache lines (the R4
// version's 2B/lane scattered stores caused 15x write amplification, 604 MB).
// Row-major outputs (Bn, Cn) stay as direct coalesced stores.
// ---------------------------------------------------------------------------
__global__ __launch_bounds__(256) void conv_silu_bf16(
    const float* __restrict__ xbcf, const float* __restrict__ cw,
    const float* __restrict__ cb, ushort_t* __restrict__ xT,
    ushort_t* __restrict__ Bn, ushort_t* __restrict__ BT,
    ushort_t* __restrict__ Cn)
{
    __shared__ ushort_t Tl[256][68];   // [c_local][row]; pad 68 -> 2-way bank alias (free)
    const int tid = threadIdx.x;
    const int c = blockIdx.x * 256 + tid;   // 0..2303
    const int rb = blockIdx.y;
    const int row0 = rb * CONV_R;
    const bool isBC = (blockIdx.x == 8);    // channels 2048..2303 = B(128) | C(128)

    const float w0 = cw[c*4+0], w1 = cw[c*4+1], w2 = cw[c*4+2], w3 = cw[c*4+3];
    const float bias = cb[c];
    float h0 = 0.f, h1 = 0.f, h2 = 0.f;
    if ((row0 & (LEN - 1)) != 0) {
        h0 = xbcf[(size_t)(row0 - 3) * CD + c];
        h1 = xbcf[(size_t)(row0 - 2) * CD + c];
        h2 = xbcf[(size_t)(row0 - 1) * CD + c];
    }
    const float* p = xbcf + (size_t)row0 * CD + c;
    for (int r = 0; r < CONV_R; r++) {
        float xin = *p;
        float a = bias + w0*h0 + w1*h1 + w2*h2 + w3*xin;
        ushort_t bv = f2bf(a / (1.f + __expf(-a)));
        Tl[tid][r] = bv;
        if (isBC) {   // row-major stores: lane = n -> coalesced 128B across lanes
            int row = row0 + r;
            if (tid < DS) Bn[(size_t)row * DS + tid] = bv;
            else          Cn[(size_t)row * DS + (tid - DS)] = bv;
        }
        h0 = h1; h1 = h2; h2 = xin;
        p += CD;
    }
    __syncthreads();

    const int seg = tid & 7;     // 8 segs x 8 rows = 64 rows
    const int clb = tid >> 3;    // 0..31 channels per pass
    if (!isBC) {
        #pragma unroll
        for (int pass = 0; pass < 8; pass++) {
            int cl = pass * 32 + clb;
            int cc = blockIdx.x * 256 + cl;
            us8 v;
            #pragma unroll
            for (int j = 0; j < 8; j++) v[j] = Tl[cl][seg * 8 + j];
            *(us8*)&xT[(size_t)cc * NTOK + row0 + seg * 8] = v;
        }
    } else {
        #pragma unroll
        for (int pass = 0; pass < 4; pass++) {
            int n = pass * 32 + clb;   // B channels 0..127
            us8 v;
            #pragma unroll
            for (int j = 0; j < 8; j++) v[j] = Tl[n][seg * 8 + j];
            *(us8*)&BT[(size_t)n * NTOK + row0 + seg * 8] = v;
        }
    }
}

// ---------------------------------------------------------------------------
// dt in FULL fp32 straight from hidden @ W_in[:, TOFF:] (exp-amplified path).
// ---------------------------------------------------------------------------
__global__ __launch_bounds__(256) void dt_proc_fp32(
    const float* __restrict__ hidden, const float* __restrict__ W_in,
    const float* __restrict__ dt_bias, const float* __restrict__ A_log,
    float* __restrict__ dtv, float* __restrict__ ldA)
{
    const int h = threadIdx.x & 31;
    const int tt = threadIdx.x >> 5;
    const int t = blockIdx.x * 8 + tt;
    const float* hr = hidden + (size_t)t * DM;
    const float* wc = W_in + TOFF + h;
    float acc = 0.f;
    #pragma unroll 4
    for (int k = 0; k < DM; k++) acc += hr[k] * wc[(size_t)k * DP];
    float v = acc + dt_bias[h];
    float sp = (v > 20.f) ? v : log1pf(expf(v));
    int idx = t * NH + h;
    dtv[idx] = sp;
    ldA[idx] = -sp * expf(A_log[h]);
}

// ---------------------------------------------------------------------------
// Phase 1 (MFMA): per (b,h,chunk): S[p][n] = sum_s (coef_s*x[s,p]) * B[s,n].
// ---------------------------------------------------------------------------
__global__ __launch_bounds__(256) void phase1_mfma(
    const ushort_t* __restrict__ xT, const ushort_t* __restrict__ BT,
    const float* __restrict__ dtv, const float* __restrict__ ldA,
    float* __restrict__ S, float* __restrict__ csum)
{
    const int blk = blockIdx.x;
    const int chunk = blk % NCH;
    const int bh = blk / NCH;
    const int h = bh % NH;
    const int b = bh / NH;
    const int tid = threadIdx.x;
    const size_t rowbase = (size_t)b * LEN + (size_t)chunk * QCH;

    __shared__ float lcp[QCH];
    __shared__ float coef[QCH];
    if (tid < QCH) lcp[tid] = ldA[(rowbase + tid) * NH + h];
    __syncthreads();
    for (int off = 1; off < QCH; off <<= 1) {
        float v = 0.f;
        if (tid < QCH && tid >= off) v = lcp[tid - off];
        __syncthreads();
        if (tid < QCH) lcp[tid] += v;
        __syncthreads();
    }
    if (tid < QCH) coef[tid] = __expf(lcp[QCH - 1] - lcp[tid]) * dtv[(rowbase + tid) * NH + h];
    if (tid == 0) csum[blk] = lcp[QCH - 1];
    __syncthreads();

    const int w = tid >> 6, lane = tid & 63;
    const int lm = lane & 15, quad = lane >> 4;
    const int nw0 = w * 32;

    f32x4 acc[4][2];
    #pragma unroll
    for (int i = 0; i < 4; i++)
        #pragma unroll
        for (int j = 0; j < 2; j++) acc[i][j] = (f32x4){0.f, 0.f, 0.f, 0.f};

    #pragma unroll
    for (int ks = 0; ks < 4; ks++) {
        const int k0 = ks * 32 + quad * 8;
        bf16x8 a[4];
        #pragma unroll
        for (int mi = 0; mi < 4; mi++)
            a[mi] = *(const bf16x8*)&xT[(size_t)(h * HD + mi * 16 + lm) * NTOK + rowbase + k0];
        float cf[8];
        #pragma unroll
        for (int j = 0; j < 8; j++) cf[j] = coef[k0 + j];
        #pragma unroll
        for (int ni = 0; ni < 2; ni++) {
            us8 raw = *(const us8*)&BT[(size_t)(nw0 + ni * 16 + lm) * NTOK + rowbase + k0];
            us8 sb;
            #pragma unroll
            for (int j = 0; j < 8; j++) sb[j] = f2bf(bf2f(raw[j]) * cf[j]);
            bf16x8 bfr = us2bf(sb);
            #pragma unroll
            for (int mi = 0; mi < 4; mi++)
                acc[mi][ni] = __builtin_amdgcn_mfma_f32_16x16x32_bf16(a[mi], bfr, acc[mi][ni], 0, 0, 0);
        }
    }
    float* Sb = S + (size_t)blk * (HD * DS);
    #pragma unroll
    for (int mi = 0; mi < 4; mi++)
        #pragma unroll
        for (int ni = 0; ni < 2; ni++)
            #pragma unroll
            for (int r = 0; r < 4; r++)
                Sb[(size_t)(mi * 16 + quad * 4 + r) * DS + nw0 + ni * 16 + lm] = acc[mi][ni][r];
}

// ---------------------------------------------------------------------------
// Phase 2: cross-chunk recurrence. Overwrites S[c] with h_start(chunk c).
// ---------------------------------------------------------------------------
__global__ __launch_bounds__(256) void phase2(
    float* __restrict__ S, const float* __restrict__ csum)
{
    const int bh = blockIdx.x;
    const int tid = threadIdx.x;
    float run[32];
    #pragma unroll
    for (int i = 0; i < 32; i++) run[i] = 0.f;
    for (int c = 0; c < NCH; c++) {
        float P = __expf(csum[bh * NCH + c]);
        float* Sb = S + (size_t)(bh * NCH + c) * (HD * DS);
        #pragma unroll
        for (int i = 0; i < 32; i++) {
            int idx = tid + i * 256;
            float s = Sb[idx];
            Sb[idx] = run[i];
            run[i] = P * run[i] + s;
        }
    }
}

// ---------------------------------------------------------------------------
// Phase 3 (MFMA): per (b,h,chunk):
//  Step A: G^T[s][t] = sum_n B[s,n]*C[t,n] via MFMA, weight+mask, bf16 G to
//          LDS in A-operand layout.
//  Step B: Y = G@X + Chat@hs^T as one fused K=256 MFMA contraction; epilogue
//          adds D*x and overwrites the block's own (dead) S region with y.
// ---------------------------------------------------------------------------
__global__ __launch_bounds__(256) void phase3_mfma(
    const ushort_t* __restrict__ xT, const ushort_t* __restrict__ Bn,
    const ushort_t* __restrict__ Cn, const float* __restrict__ dtv,
    const float* __restrict__ ldA, const float* __restrict__ Dvec,
    float* __restrict__ S)
{
    const int tid = threadIdx.x;
    const int blk = blockIdx.x;
    const int chunk = blk % NCH;
    const int bh = blk / NCH;
    const int h = bh % NH;
    const int b = bh / NH;
    const size_t rowbase = (size_t)b * LEN + (size_t)chunk * QCH;

    __shared__ float lcp[QCH];
    __shared__ float dts[QCH];
    __shared__ __align__(16) ushort_t Gs[QCH * GLD];

    if (tid < QCH) {
        lcp[tid] = ldA[(rowbase + tid) * NH + h];
        dts[tid] = dtv[(rowbase + tid) * NH + h];
    }
    __syncthreads();
    for (int off = 1; off < QCH; off <<= 1) {
        float v = 0.f;
        if (tid < QCH && tid >= off) v = lcp[tid - off];
        __syncthreads();
        if (tid < QCH) lcp[tid] += v;
        __syncthreads();
    }

    const int w = tid >> 6, lane = tid & 63;
    const int lm = lane & 15, quad = lane >> 4;

    // ---- Step A ----
    {
        const int sw0 = w * 32;
        f32x4 acc[2][8];
        #pragma unroll
        for (int si = 0; si < 2; si++)
            #pragma unroll
            for (int ti = 0; ti < 8; ti++) acc[si][ti] = (f32x4){0.f, 0.f, 0.f, 0.f};

        #pragma unroll
        for (int ks = 0; ks < 4; ks++) {
            const int k0 = ks * 32 + quad * 8;
            bf16x8 a0 = *(const bf16x8*)&Bn[(rowbase + sw0 + lm) * DS + k0];
            bf16x8 a1 = *(const bf16x8*)&Bn[(rowbase + sw0 + 16 + lm) * DS + k0];
            #pragma unroll
            for (int ti = 0; ti < 8; ti++) {
                bf16x8 cf = *(const bf16x8*)&Cn[(rowbase + ti * 16 + lm) * DS + k0];
                acc[0][ti] = __builtin_amdgcn_mfma_f32_16x16x32_bf16(a0, cf, acc[0][ti], 0, 0, 0);
                acc[1][ti] = __builtin_amdgcn_mfma_f32_16x16x32_bf16(a1, cf, acc[1][ti], 0, 0, 0);
            }
        }
        #pragma unroll
        for (int si = 0; si < 2; si++)
            #pragma unroll
            for (int ti = 0; ti < 8; ti++) {
                int t = ti * 16 + lm;
                float lt = lcp[t];
                ushort_t pk[4];
                #pragma unroll
                for (int r = 0; r < 4; r++) {
                    int s = sw0 + si * 16 + quad * 4 + r;
                    float wv = (s <= t) ? (__expf(lt - lcp[s]) * dts[s]) : 0.f;
                    pk[r] = f2bf(acc[si][ti][r] * wv);
                }
                *(ushort4*)&Gs[t * GLD + sw0 + si * 16 + quad * 4] = *(ushort4*)pk;
            }
    }
    __syncthreads();

    // ---- Step B ----
    const int tw0 = w * 32;
    const float* hsb = S + (size_t)blk * (HD * DS);
    f32x4 acc2[2][4];
    #pragma unroll
    for (int ti = 0; ti < 2; ti++)
        #pragma unroll
        for (int pi = 0; pi < 4; pi++) acc2[ti][pi] = (f32x4){0.f, 0.f, 0.f, 0.f};

    #pragma unroll
    for (int ks = 0; ks < 8; ks++) {
        bf16x8 a[2], bb[4];
        if (ks < 4) {
            const int k0 = ks * 32 + quad * 8;
            a[0] = *(const bf16x8*)&Gs[(tw0 + lm) * GLD + k0];
            a[1] = *(const bf16x8*)&Gs[(tw0 + 16 + lm) * GLD + k0];
            #pragma unroll
            for (int pi = 0; pi < 4; pi++)
                bb[pi] = *(const bf16x8*)&xT[(size_t)(h * HD + pi * 16 + lm) * NTOK + rowbase + k0];
        } else {
            const int k0 = (ks - 4) * 32 + quad * 8;
            #pragma unroll
            for (int ti = 0; ti < 2; ti++) {
                int t = tw0 + ti * 16 + lm;
                float sc = __expf(lcp[t]);
                us8 raw = *(const us8*)&Cn[(rowbase + t) * DS + k0];
                us8 sb;
                #pragma unroll
                for (int j = 0; j < 8; j++) sb[j] = f2bf(bf2f(raw[j]) * sc);
                a[ti] = us2bf(sb);
            }
            #pragma unroll
            for (int pi = 0; pi < 4; pi++) {
                const float* hp = &hsb[(size_t)(pi * 16 + lm) * DS + k0];
                float4 h0 = *(const float4*)hp;
                float4 h1 = *(const float4*)(hp + 4);
                us8 sb;
                sb[0] = f2bf(h0.x); sb[1] = f2bf(h0.y); sb[2] = f2bf(h0.z); sb[3] = f2bf(h0.w);
                sb[4] = f2bf(h1.x); sb[5] = f2bf(h1.y); sb[6] = f2bf(h1.z); sb[7] = f2bf(h1.w);
                bb[pi] = us2bf(sb);
            }
        }
        #pragma unroll
        for (int ti = 0; ti < 2; ti++)
            #pragma unroll
            for (int pi = 0; pi < 4; pi++)
                acc2[ti][pi] = __builtin_amdgcn_mfma_f32_16x16x32_bf16(a[ti], bb[pi], acc2[ti][pi], 0, 0, 0);
    }

    __syncthreads();   // all hs reads complete before overwrite
    const float Dh = Dvec[h];
    float* yb = S + (size_t)blk * (HD * DS);
    #pragma unroll
    for (int ti = 0; ti < 2; ti++)
        #pragma unroll
        for (int pi = 0; pi < 4; pi++) {
            int tb = tw0 + ti * 16 + quad * 4;
            ushort4 xv = *(const ushort4*)&xT[(size_t)(h * HD + pi * 16 + lm) * NTOK + rowbase + tb];
            const ushort_t* xe = (const ushort_t*)&xv;
            #pragma unroll
            for (int r = 0; r < 4; r++) {
                float y = acc2[ti][pi][r] + Dh * bf2f(xe[r]);
                yb[(size_t)(tb + r) * HD + pi * 16 + lm] = y;
            }
        }
}

// ---------------------------------------------------------------------------
// Gate (y * silu(z)) + RMSNorm over DI. z from bf16; writes bf16 y_norm.
// ---------------------------------------------------------------------------
__global__ __launch_bounds__(256) void gate_rms(
    const ushort_t* __restrict__ zb, const float* __restrict__ Sy,
    const float* __restrict__ nw, ushort_t* __restrict__ ynb)
{
    const int row = blockIdx.x;
    const int tid = threadIdx.x;
    const int b = row >> 11;
    const int l = row & (LEN - 1);
    const int chunk = l >> 7;
    const int t = l & (QCH - 1);
    const ushort_t* zr = zb + (size_t)row * DI;
    float g[8];
    float ss = 0.f;
    #pragma unroll
    for (int i = 0; i < 8; i++) {
        int c = tid + i * 256;
        int h = c >> 6;
        int p = c & 63;
        float y = Sy[((size_t)((b * NH + h) * NCH + chunk)) * (HD * DS) + t * HD + p];
        float z = bf2f(zr[c]);
        float sg = z / (1.f + __expf(-z));
        float v = y * sg;
        g[i] = v;
        ss += v * v;
    }
    #pragma unroll
    for (int off = 32; off > 0; off >>= 1) ss += __shfl_down(ss, off, 64);
    __shared__ float red[4];
    if ((tid & 63) == 0) red[tid >> 6] = ss;
    __syncthreads();
    float tot = red[0] + red[1] + red[2] + red[3];
    float r = rsqrtf(tot * (1.f / DI) + 1e-5f);
    #pragma unroll
    for (int i = 0; i < 8; i++) {
        int c = tid + i * 256;
        ynb[(size_t)row * DI + c] = f2bf(g[i] * r * nw[c]);
    }
}

// ---------------------------------------------------------------------------
extern "C" void kernel_launch(void* const* d_in, const int* in_sizes, int n_in,
                              void* d_out, int out_size, void* d_ws, size_t ws_size,
                              hipStream_t stream)
{
    const float* hidden  = (const float*)d_in[0];
    const float* W_in    = (const float*)d_in[1];
    const float* conv_w  = (const float*)d_in[2];
    const float* conv_b  = (const float*)d_in[3];
    const float* dt_bias = (const float*)d_in[4];
    const float* A_log   = (const float*)d_in[5];
    const float* Dv      = (const float*)d_in[6];
    const float* norm_w  = (const float*)d_in[7];
    const float* W_out   = (const float*)d_in[8];
    float* out = (float*)d_out;

    char* ws = (char*)d_ws;
    size_t o = 0;
    ushort_t* zb  = (ushort_t*)(ws + o); o += (size_t)NTOK * DI * 2;               // 33.6 MB
    float* xbcf   = (float*)(ws + o);    o += (size_t)NTOK * CD * 4;               // 75.5 MB
    float* S      = (float*)(ws + o);    o += (size_t)BSZ * NH * NCH * HD * DS * 4;// 67.1 MB
    ushort_t* xT  = (ushort_t*)(ws + o); o += (size_t)DI * NTOK * 2;               // 33.6 MB
    ushort_t* Bn  = (ushort_t*)(ws + o); o += (size_t)NTOK * DS * 2;               // 2.1 MB
    ushort_t* BT  = (ushort_t*)(ws + o); o += (size_t)DS * NTOK * 2;               // 2.1 MB
    ushort_t* Cn  = (ushort_t*)(ws + o); o += (size_t)NTOK * DS * 2;               // 2.1 MB
    float* dtv    = (float*)(ws + o);    o += (size_t)NTOK * NH * 4;               // 1.05 MB
    float* ldA    = (float*)(ws + o);    o += (size_t)NTOK * NH * 4;               // 1.05 MB
    float* csum   = (float*)(ws + o);    o += (size_t)BSZ * NH * NCH * 4;          // 8 KB
    // total ~218.1 MB
    // Aliases (dead-region reuse):
    ushort_t* Ah  = (ushort_t*)S;                                   // pre-phase1
    ushort_t* W1t = (ushort_t*)((char*)S + (size_t)NTOK * DM * 2);  // pre-phase1
    ushort_t* Wot = (ushort_t*)S;                                   // post-gate_rms
    ushort_t* ynb = (ushort_t*)xbcf;                                // post-conv

    // 1) bf16 conversions for GEMM1
    cvt_bf16<<<(NTOK * DM) / 1024, 256, 0, stream>>>(hidden, Ah);
    transpose_cvt<<<dim3(NPAD / 32, DM / 32), 256, 0, stream>>>(W_in, W1t, DM, DP, DP);
    // 2) GEMM1 split: z part (bf16 out), xBC part (fp32 out)
    gemm_bf16<true><<<dim3(DI / 128, NTOK / 128), 256, 0, stream>>>(
        Ah, W1t, zb, DM, DM, DM, DI, DI);
    gemm_bf16<false><<<dim3(19, NTOK / 128), 256, 0, stream>>>(
        Ah, W1t + (size_t)DI * DM, xbcf, DM, DM, DM, CD, CD);
    // 3) conv + SiLU -> bf16 operand caches (LDS-transposed coalesced stores)
    conv_silu_bf16<<<dim3(CD / 256, NRB), 256, 0, stream>>>(
        xbcf, conv_w, conv_b, xT, Bn, BT, Cn);
    // 4) dt in fp32
    dt_proc_fp32<<<NTOK / 8, 256, 0, stream>>>(hidden, W_in, dt_bias, A_log, dtv, ldA);
    // 5) chunk states (MFMA) — overwrites Ah/W1t alias region (dead)
    phase1_mfma<<<BSZ * NH * NCH, 256, 0, stream>>>(xT, BT, dtv, ldA, S, csum);
    // 6) cross-chunk recurrence
    phase2<<<BSZ * NH, 256, 0, stream>>>(S, csum);
    // 7) per-chunk outputs (MFMA) — overwrites S with y
    phase3_mfma<<<BSZ * NH * NCH, 256, 0, stream>>>(xT, Bn, Cn, dtv, ldA, Dv, S);
    // 8) gate + RMSNorm -> bf16 y_norm (into xbcf alias)
    gate_rms<<<NTOK, 256, 0, stream>>>(zb, S, norm_w, ynb);
    // 9) W_out transpose (S dead), then out = y_norm @ W_out
    transpose_cvt<<<dim3(DM / 32, DI / 32), 256, 0, stream>>>(W_out, Wot, DI, DM, DM);
    gemm_bf16<false><<<dim3(DM / 128, NTOK / 128), 256, 0, stream>>>(
        ynb, Wot, out, DI, DI, DI, DM, DM);
}

// Round 6
// 577.491 us; speedup vs baseline: 1.3996x; 1.0749x over previous
//
#include <hip/hip_runtime.h>
#include <math.h>

#define BSZ 4
#define LEN 2048
#define DM 1024
#define DI 2048
#define HD 64      // HEADDIM (p)
#define NH 32      // NHEADS
#define DS 128     // D_STATE (n)
#define CD 2304    // CONV_DIM
#define DP 4384    // D_IN_PROJ
#define NTOK (BSZ*LEN)   // 8192
#define QCH 128          // chunk length
#define NCH (LEN/QCH)    // 16 chunks
#define TOFF (DP-NH)     // 4352: dt raw cols in W_in

#define CONV_R 64
#define NRB (NTOK/CONV_R)
#define NPAD 4480        // W_in columns padded to 35*128 (2048 z + 2432 xBC-pad)
#define GLD 136          // Gs LDS leading dim (bf16 elems)

typedef unsigned short ushort_t;
typedef __bf16 bf16x8 __attribute__((ext_vector_type(8)));
typedef ushort_t us8 __attribute__((ext_vector_type(8)));
typedef float f32x4 __attribute__((ext_vector_type(4)));

__device__ __forceinline__ ushort_t f2bf(float f) {
    unsigned u = __float_as_uint(f);
    unsigned r = (u + 0x7FFFu + ((u >> 16) & 1u)) >> 16;
    return (ushort_t)r;
}
__device__ __forceinline__ float bf2f(ushort_t u) {
    return __uint_as_float(((unsigned)u) << 16);
}
__device__ __forceinline__ bf16x8 us2bf(us8 v) {
    union { us8 u; bf16x8 b; } x; x.u = v; return x.b;
}

__device__ __forceinline__ void gl_lds16(const void* g, void* l) {
    __builtin_amdgcn_global_load_lds(
        (const __attribute__((address_space(1))) void*)g,
        (__attribute__((address_space(3))) void*)l, 16, 0, 0);
}

// ---------------------------------------------------------------------------
// fp32 -> bf16 elementwise (hidden). 4 elems/thread.
// ---------------------------------------------------------------------------
__global__ __launch_bounds__(256) void cvt_bf16(
    const float* __restrict__ A, ushort_t* __restrict__ Ab)
{
    size_t i = ((size_t)blockIdx.x * 256 + threadIdx.x) * 4;
    float4 v = *(const float4*)(A + i);
    ushort_t o[4] = { f2bf(v.x), f2bf(v.y), f2bf(v.z), f2bf(v.w) };
    *(uint2*)(Ab + i) = *(uint2*)o;
}

// ---------------------------------------------------------------------------
// W[k][n] fp32 (ld=ldw) -> Wt[n][k] bf16 (ld=K), zero-pad for n >= N.
// ---------------------------------------------------------------------------
__global__ __launch_bounds__(256) void transpose_cvt(
    const float* __restrict__ W, ushort_t* __restrict__ Wt,
    int K, int N, int ldw)
{
    __shared__ float T[32][33];
    const int n0 = blockIdx.x * 32;
    const int k0 = blockIdx.y * 32;
    const int tid = threadIdx.x;
    #pragma unroll
    for (int l = 0; l < 4; l++) {
        int idx = tid + l * 256;
        int ki = idx >> 5, nj = idx & 31;
        int n = n0 + nj;
        T[ki][nj] = (n < N) ? W[(size_t)(k0 + ki) * ldw + n] : 0.f;
    }
    __syncthreads();
    #pragma unroll
    for (int l = 0; l < 4; l++) {
        int idx = tid + l * 256;
        int nj = idx >> 5, ki = idx & 31;
        Wt[(size_t)(n0 + nj) * K + k0 + ki] = f2bf(T[ki][nj]);
    }
}

// ---------------------------------------------------------------------------
// bf16 MFMA GEMM (B^T form): C[m][n] = sum_k A[m][k] * Bt[n][k].
// 128x128 tile, BK=32, m97 structure. OB: bf16 output else fp32.
// ---------------------------------------------------------------------------
template <bool OB>
__global__ __launch_bounds__(256) void gemm_bf16(
    const ushort_t* __restrict__ A, const ushort_t* __restrict__ Bt,
    void* __restrict__ Cp, int K, int lda, int ldb, int ldc, int nmax)
{
    __shared__ __align__(16) ushort_t As[128 * 32];
    __shared__ __align__(16) ushort_t Bs[128 * 32];
    const int tid = threadIdx.x;
    const int n0 = blockIdx.x * 128;
    const int m0 = blockIdx.y * 128;
    const int lane = tid & 63;
    const int w = tid >> 6;
    const int wm = w >> 1, wn = w & 1;
    const int lm = lane & 15, quad = lane >> 4;

    const int srow = tid >> 2;
    const int skq = (tid & 3) * 8;
    const ushort_t* ga0 = A + (size_t)(m0 + srow) * lda + skq;
    const ushort_t* ga1 = A + (size_t)(m0 + 64 + srow) * lda + skq;
    const ushort_t* gb0 = Bt + (size_t)(n0 + srow) * ldb + skq;
    const ushort_t* gb1 = Bt + (size_t)(n0 + 64 + srow) * ldb + skq;
    ushort_t* la0 = &As[srow * 32 + skq];
    ushort_t* la1 = &As[(64 + srow) * 32 + skq];
    ushort_t* lb0 = &Bs[srow * 32 + skq];
    ushort_t* lb1 = &Bs[(64 + srow) * 32 + skq];

    f32x4 acc[4][4];
    #pragma unroll
    for (int i = 0; i < 4; i++)
        #pragma unroll
        for (int j = 0; j < 4; j++) acc[i][j] = (f32x4){0.f, 0.f, 0.f, 0.f};

    for (int k0 = 0; k0 < K; k0 += 32) {
        gl_lds16(ga0, la0);
        gl_lds16(ga1, la1);
        gl_lds16(gb0, lb0);
        gl_lds16(gb1, lb1);
        ga0 += 32; ga1 += 32; gb0 += 32; gb1 += 32;
        __syncthreads();
        bf16x8 af[4], bfr[4];
        #pragma unroll
        for (int i = 0; i < 4; i++)
            af[i] = *(const bf16x8*)&As[(wm * 64 + i * 16 + lm) * 32 + quad * 8];
        #pragma unroll
        for (int j = 0; j < 4; j++)
            bfr[j] = *(const bf16x8*)&Bs[(wn * 64 + j * 16 + lm) * 32 + quad * 8];
        #pragma unroll
        for (int i = 0; i < 4; i++)
            #pragma unroll
            for (int j = 0; j < 4; j++)
                acc[i][j] = __builtin_amdgcn_mfma_f32_16x16x32_bf16(af[i], bfr[j], acc[i][j], 0, 0, 0);
        __syncthreads();
    }

    #pragma unroll
    for (int i = 0; i < 4; i++) {
        int row = m0 + wm * 64 + i * 16 + quad * 4;
        #pragma unroll
        for (int j = 0; j < 4; j++) {
            int col = n0 + wn * 64 + j * 16 + lm;
            if (col < nmax) {
                #pragma unroll
                for (int r = 0; r < 4; r++) {
                    if (OB)
                        ((ushort_t*)Cp)[(size_t)(row + r) * ldc + col] = f2bf(acc[i][j][r]);
                    else
                        ((float*)Cp)[(size_t)(row + r) * ldc + col] = acc[i][j][r];
                }
            }
        }
    }
}

// ---------------------------------------------------------------------------
// Depthwise causal conv (w=4) + bias + SiLU -> bf16 operand caches.
// Reads bf16 xbcb [NTOK][CD] (coalesced: lane = channel).
// xT/BT (transposed) go through an LDS tile -> 16B stores over 8 consecutive
// rows (avoids the R4 2B-scatter 15x write amplification). Bn/Cn direct.
// ---------------------------------------------------------------------------
__global__ __launch_bounds__(256) void conv_silu_bf16(
    const ushort_t* __restrict__ xbcb, const float* __restrict__ cw,
    const float* __restrict__ cb, ushort_t* __restrict__ xT,
    ushort_t* __restrict__ Bn, ushort_t* __restrict__ BT,
    ushort_t* __restrict__ Cn)
{
    __shared__ ushort_t Tl[256][68];
    const int tid = threadIdx.x;
    const int c = blockIdx.x * 256 + tid;
    const int rb = blockIdx.y;
    const int row0 = rb * CONV_R;
    const bool isBC = (blockIdx.x == 8);

    const float w0 = cw[c*4+0], w1 = cw[c*4+1], w2 = cw[c*4+2], w3 = cw[c*4+3];
    const float bias = cb[c];
    float h0 = 0.f, h1 = 0.f, h2 = 0.f;
    if ((row0 & (LEN - 1)) != 0) {
        h0 = bf2f(xbcb[(size_t)(row0 - 3) * CD + c]);
        h1 = bf2f(xbcb[(size_t)(row0 - 2) * CD + c]);
        h2 = bf2f(xbcb[(size_t)(row0 - 1) * CD + c]);
    }
    const ushort_t* p = xbcb + (size_t)row0 * CD + c;
    for (int r = 0; r < CONV_R; r++) {
        float xin = bf2f(*p);
        float a = bias + w0*h0 + w1*h1 + w2*h2 + w3*xin;
        ushort_t bv = f2bf(a / (1.f + __expf(-a)));
        Tl[tid][r] = bv;
        if (isBC) {
            int row = row0 + r;
            if (tid < DS) Bn[(size_t)row * DS + tid] = bv;
            else          Cn[(size_t)row * DS + (tid - DS)] = bv;
        }
        h0 = h1; h1 = h2; h2 = xin;
        p += CD;
    }
    __syncthreads();

    const int seg = tid & 7;
    const int clb = tid >> 3;
    if (!isBC) {
        #pragma unroll
        for (int pass = 0; pass < 8; pass++) {
            int cl = pass * 32 + clb;
            int cc = blockIdx.x * 256 + cl;
            us8 v;
            #pragma unroll
            for (int j = 0; j < 8; j++) v[j] = Tl[cl][seg * 8 + j];
            *(us8*)&xT[(size_t)cc * NTOK + row0 + seg * 8] = v;
        }
    } else {
        #pragma unroll
        for (int pass = 0; pass < 4; pass++) {
            int n = pass * 32 + clb;
            us8 v;
            #pragma unroll
            for (int j = 0; j < 8; j++) v[j] = Tl[n][seg * 8 + j];
            *(us8*)&BT[(size_t)n * NTOK + row0 + seg * 8] = v;
        }
    }
}

// ---------------------------------------------------------------------------
// dt in FULL fp32 straight from hidden @ W_in[:, TOFF:] (exp-amplified path).
// 4-way split accumulators for ILP.
// ---------------------------------------------------------------------------
__global__ __launch_bounds__(256) void dt_proc_fp32(
    const float* __restrict__ hidden, const float* __restrict__ W_in,
    const float* __restrict__ dt_bias, const float* __restrict__ A_log,
    float* __restrict__ dtv, float* __restrict__ ldA)
{
    const int h = threadIdx.x & 31;
    const int tt = threadIdx.x >> 5;
    const int t = blockIdx.x * 8 + tt;
    const float* hr = hidden + (size_t)t * DM;
    const float* wc = W_in + TOFF + h;
    float a0 = 0.f, a1 = 0.f, a2 = 0.f, a3 = 0.f;
    for (int k = 0; k < DM; k += 4) {
        a0 += hr[k+0] * wc[(size_t)(k+0) * DP];
        a1 += hr[k+1] * wc[(size_t)(k+1) * DP];
        a2 += hr[k+2] * wc[(size_t)(k+2) * DP];
        a3 += hr[k+3] * wc[(size_t)(k+3) * DP];
    }
    float v = (a0 + a1) + (a2 + a3) + dt_bias[h];
    float sp = (v > 20.f) ? v : log1pf(expf(v));
    int idx = t * NH + h;
    dtv[idx] = sp;
    ldA[idx] = -sp * expf(A_log[h]);
}

// ---------------------------------------------------------------------------
// Per-(b,h,chunk) prefix scan of ldA, hoisted out of phase1/phase3.
// One wave per block, shfl-based, zero barriers. Emits lcp, dts (chunk
// layout), coef (phase1's B-scale), and csum.
// ---------------------------------------------------------------------------
__global__ __launch_bounds__(64) void scan_chunk(
    const float* __restrict__ dtv, const float* __restrict__ ldA,
    float* __restrict__ lcpb, float* __restrict__ dtsb,
    float* __restrict__ coefb, float* __restrict__ csum)
{
    const int blk = blockIdx.x;            // bh*NCH + chunk
    const int chunk = blk % NCH;
    const int bh = blk / NCH;
    const int h = bh % NH;
    const int b = bh / NH;
    const int lane = threadIdx.x;
    const size_t rowbase = (size_t)b * LEN + (size_t)chunk * QCH;
    const int t0 = 2 * lane, t1 = 2 * lane + 1;
    float v0 = ldA[(rowbase + t0) * NH + h];
    float v1 = ldA[(rowbase + t1) * NH + h];
    float d0 = dtv[(rowbase + t0) * NH + h];
    float d1 = dtv[(rowbase + t1) * NH + h];
    float pair = v0 + v1;
    #pragma unroll
    for (int off = 1; off < 64; off <<= 1) {
        float n = __shfl_up(pair, off, 64);
        if (lane >= off) pair += n;
    }
    float l1 = pair, l0 = pair - v1;
    float total = __shfl(pair, 63, 64);
    size_t base = (size_t)blk * QCH;
    *(float2*)&lcpb[base + t0] = make_float2(l0, l1);
    *(float2*)&dtsb[base + t0] = make_float2(d0, d1);
    *(float2*)&coefb[base + t0] =
        make_float2(__expf(total - l0) * d0, __expf(total - l1) * d1);
    if (lane == 63) csum[blk] = total;
}

// ---------------------------------------------------------------------------
// Phase 1 (MFMA): per (b,h,chunk): S[p][n] = sum_s (coef_s*x[s,p]) * B[s,n].
// ---------------------------------------------------------------------------
__global__ __launch_bounds__(256) void phase1_mfma(
    const ushort_t* __restrict__ xT, const ushort_t* __restrict__ BT,
    const float* __restrict__ coefb, float* __restrict__ S)
{
    const int blk = blockIdx.x;
    const int chunk = blk % NCH;
    const int bh = blk / NCH;
    const int h = bh % NH;
    const int b = bh / NH;
    const int tid = threadIdx.x;
    const size_t rowbase = (size_t)b * LEN + (size_t)chunk * QCH;

    __shared__ float coef[QCH];
    if (tid < QCH) coef[tid] = coefb[(size_t)blk * QCH + tid];
    __syncthreads();

    const int w = tid >> 6, lane = tid & 63;
    const int lm = lane & 15, quad = lane >> 4;
    const int nw0 = w * 32;

    f32x4 acc[4][2];
    #pragma unroll
    for (int i = 0; i < 4; i++)
        #pragma unroll
        for (int j = 0; j < 2; j++) acc[i][j] = (f32x4){0.f, 0.f, 0.f, 0.f};

    #pragma unroll
    for (int ks = 0; ks < 4; ks++) {
        const int k0 = ks * 32 + quad * 8;
        bf16x8 a[4];
        #pragma unroll
        for (int mi = 0; mi < 4; mi++)
            a[mi] = *(const bf16x8*)&xT[(size_t)(h * HD + mi * 16 + lm) * NTOK + rowbase + k0];
        float cf[8];
        #pragma unroll
        for (int j = 0; j < 8; j++) cf[j] = coef[k0 + j];
        #pragma unroll
        for (int ni = 0; ni < 2; ni++) {
            us8 raw = *(const us8*)&BT[(size_t)(nw0 + ni * 16 + lm) * NTOK + rowbase + k0];
            us8 sb;
            #pragma unroll
            for (int j = 0; j < 8; j++) sb[j] = f2bf(bf2f(raw[j]) * cf[j]);
            bf16x8 bfr = us2bf(sb);
            #pragma unroll
            for (int mi = 0; mi < 4; mi++)
                acc[mi][ni] = __builtin_amdgcn_mfma_f32_16x16x32_bf16(a[mi], bfr, acc[mi][ni], 0, 0, 0);
        }
    }
    float* Sb = S + (size_t)blk * (HD * DS);
    #pragma unroll
    for (int mi = 0; mi < 4; mi++)
        #pragma unroll
        for (int ni = 0; ni < 2; ni++)
            #pragma unroll
            for (int r = 0; r < 4; r++)
                Sb[(size_t)(mi * 16 + quad * 4 + r) * DS + nw0 + ni * 16 + lm] = acc[mi][ni][r];
}

// ---------------------------------------------------------------------------
// Phase 2: cross-chunk recurrence. Reads fp32 S (chunk states), emits bf16
// h_start into hsb. 8-way element split for CU coverage (1024 blocks).
// ---------------------------------------------------------------------------
__global__ __launch_bounds__(256) void phase2(
    const float* __restrict__ S, const float* __restrict__ csum,
    ushort_t* __restrict__ hsb)
{
    const int bh = blockIdx.x >> 3;
    const int esl = blockIdx.x & 7;
    const int tid = threadIdx.x;
    const int eb = esl * 1024 + tid;
    float run[4] = {0.f, 0.f, 0.f, 0.f};
    for (int c = 0; c < NCH; c++) {
        float P = __expf(csum[bh * NCH + c]);
        size_t base = (size_t)(bh * NCH + c) * (HD * DS);
        #pragma unroll
        for (int i = 0; i < 4; i++) {
            size_t idx = base + eb + i * 256;
            float s = S[idx];
            hsb[idx] = f2bf(run[i]);
            run[i] = P * run[i] + s;
        }
    }
}

// ---------------------------------------------------------------------------
// Phase 3 (MFMA): per (b,h,chunk):
//  Step A: G^T[s][t] = sum_n B[s,n]*C[t,n] via MFMA, weight+mask, bf16 G to
//          LDS in A-operand layout.
//  Step B: Y = G@X + Chat@hs^T as one fused K=256 MFMA contraction (hs is
//          bf16 -> direct fragment loads). Epilogue adds D*x and writes
//          bf16 y into ybuf (dead-S alias).
// ---------------------------------------------------------------------------
__global__ __launch_bounds__(256) void phase3_mfma(
    const ushort_t* __restrict__ xT, const ushort_t* __restrict__ Bn,
    const ushort_t* __restrict__ Cn, const ushort_t* __restrict__ hsb,
    const float* __restrict__ lcpb, const float* __restrict__ dtsb,
    const float* __restrict__ Dvec, ushort_t* __restrict__ ybuf)
{
    const int tid = threadIdx.x;
    const int blk = blockIdx.x;
    const int chunk = blk % NCH;
    const int bh = blk / NCH;
    const int h = bh % NH;
    const int b = bh / NH;
    const size_t rowbase = (size_t)b * LEN + (size_t)chunk * QCH;

    __shared__ float lcp[QCH];
    __shared__ float dts[QCH];
    __shared__ __align__(16) ushort_t Gs[QCH * GLD];

    if (tid < QCH) {
        lcp[tid] = lcpb[(size_t)blk * QCH + tid];
        dts[tid] = dtsb[(size_t)blk * QCH + tid];
    }
    __syncthreads();

    const int w = tid >> 6, lane = tid & 63;
    const int lm = lane & 15, quad = lane >> 4;

    // ---- Step A ----
    {
        const int sw0 = w * 32;
        f32x4 acc[2][8];
        #pragma unroll
        for (int si = 0; si < 2; si++)
            #pragma unroll
            for (int ti = 0; ti < 8; ti++) acc[si][ti] = (f32x4){0.f, 0.f, 0.f, 0.f};

        #pragma unroll
        for (int ks = 0; ks < 4; ks++) {
            const int k0 = ks * 32 + quad * 8;
            bf16x8 a0 = *(const bf16x8*)&Bn[(rowbase + sw0 + lm) * DS + k0];
            bf16x8 a1 = *(const bf16x8*)&Bn[(rowbase + sw0 + 16 + lm) * DS + k0];
            #pragma unroll
            for (int ti = 0; ti < 8; ti++) {
                bf16x8 cf = *(const bf16x8*)&Cn[(rowbase + ti * 16 + lm) * DS + k0];
                acc[0][ti] = __builtin_amdgcn_mfma_f32_16x16x32_bf16(a0, cf, acc[0][ti], 0, 0, 0);
                acc[1][ti] = __builtin_amdgcn_mfma_f32_16x16x32_bf16(a1, cf, acc[1][ti], 0, 0, 0);
            }
        }
        #pragma unroll
        for (int si = 0; si < 2; si++)
            #pragma unroll
            for (int ti = 0; ti < 8; ti++) {
                int t = ti * 16 + lm;
                float lt = lcp[t];
                ushort_t pk[4];
                #pragma unroll
                for (int r = 0; r < 4; r++) {
                    int s = sw0 + si * 16 + quad * 4 + r;
                    float wv = (s <= t) ? (__expf(lt - lcp[s]) * dts[s]) : 0.f;
                    pk[r] = f2bf(acc[si][ti][r] * wv);
                }
                *(ushort4*)&Gs[t * GLD + sw0 + si * 16 + quad * 4] = *(ushort4*)pk;
            }
    }
    __syncthreads();

    // ---- Step B ----
    const int tw0 = w * 32;
    const ushort_t* hsb_ = hsb + (size_t)blk * (HD * DS);
    f32x4 acc2[2][4];
    #pragma unroll
    for (int ti = 0; ti < 2; ti++)
        #pragma unroll
        for (int pi = 0; pi < 4; pi++) acc2[ti][pi] = (f32x4){0.f, 0.f, 0.f, 0.f};

    #pragma unroll
    for (int ks = 0; ks < 8; ks++) {
        bf16x8 a[2], bb[4];
        if (ks < 4) {
            const int k0 = ks * 32 + quad * 8;
            a[0] = *(const bf16x8*)&Gs[(tw0 + lm) * GLD + k0];
            a[1] = *(const bf16x8*)&Gs[(tw0 + 16 + lm) * GLD + k0];
            #pragma unroll
            for (int pi = 0; pi < 4; pi++)
                bb[pi] = *(const bf16x8*)&xT[(size_t)(h * HD + pi * 16 + lm) * NTOK + rowbase + k0];
        } else {
            const int k0 = (ks - 4) * 32 + quad * 8;
            #pragma unroll
            for (int ti = 0; ti < 2; ti++) {
                int t = tw0 + ti * 16 + lm;
                float sc = __expf(lcp[t]);
                us8 raw = *(const us8*)&Cn[(rowbase + t) * DS + k0];
                us8 sb;
                #pragma unroll
                for (int j = 0; j < 8; j++) sb[j] = f2bf(bf2f(raw[j]) * sc);
                a[ti] = us2bf(sb);
            }
            #pragma unroll
            for (int pi = 0; pi < 4; pi++)
                bb[pi] = *(const bf16x8*)&hsb_[(size_t)(pi * 16 + lm) * DS + k0];
        }
        #pragma unroll
        for (int ti = 0; ti < 2; ti++)
            #pragma unroll
            for (int pi = 0; pi < 4; pi++)
                acc2[ti][pi] = __builtin_amdgcn_mfma_f32_16x16x32_bf16(a[ti], bb[pi], acc2[ti][pi], 0, 0, 0);
    }

    const float Dh = Dvec[h];
    ushort_t* yb = ybuf + (size_t)blk * (HD * QCH);   // [t][p]
    #pragma unroll
    for (int ti = 0; ti < 2; ti++)
        #pragma unroll
        for (int pi = 0; pi < 4; pi++) {
            int tb = tw0 + ti * 16 + quad * 4;
            ushort4 xv = *(const ushort4*)&xT[(size_t)(h * HD + pi * 16 + lm) * NTOK + rowbase + tb];
            const ushort_t* xe = (const ushort_t*)&xv;
            #pragma unroll
            for (int r = 0; r < 4; r++) {
                float y = acc2[ti][pi][r] + Dh * bf2f(xe[r]);
                yb[(size_t)(tb + r) * HD + pi * 16 + lm] = f2bf(y);
            }
        }
}

// ---------------------------------------------------------------------------
// Gate (y * silu(z)) + RMSNorm over DI. y and z from bf16; writes bf16 y_norm.
// ---------------------------------------------------------------------------
__global__ __launch_bounds__(256) void gate_rms(
    const ushort_t* __restrict__ zb, const ushort_t* __restrict__ ybuf,
    const float* __restrict__ nw, ushort_t* __restrict__ ynb)
{
    const int row = blockIdx.x;
    const int tid = threadIdx.x;
    const int b = row >> 11;
    const int l = row & (LEN - 1);
    const int chunk = l >> 7;
    const int t = l & (QCH - 1);
    const ushort_t* zr = zb + (size_t)row * DI;
    float g[8];
    float ss = 0.f;
    #pragma unroll
    for (int i = 0; i < 8; i++) {
        int c = tid + i * 256;
        int h = c >> 6;
        int p = c & 63;
        float y = bf2f(ybuf[((size_t)((b * NH + h) * NCH + chunk)) * (HD * QCH) + t * HD + p]);
        float z = bf2f(zr[c]);
        float sg = z / (1.f + __expf(-z));
        float v = y * sg;
        g[i] = v;
        ss += v * v;
    }
    #pragma unroll
    for (int off = 32; off > 0; off >>= 1) ss += __shfl_down(ss, off, 64);
    __shared__ float red[4];
    if ((tid & 63) == 0) red[tid >> 6] = ss;
    __syncthreads();
    float tot = red[0] + red[1] + red[2] + red[3];
    float r = rsqrtf(tot * (1.f / DI) + 1e-5f);
    #pragma unroll
    for (int i = 0; i < 8; i++) {
        int c = tid + i * 256;
        ynb[(size_t)row * DI + c] = f2bf(g[i] * r * nw[c]);
    }
}

// ---------------------------------------------------------------------------
extern "C" void kernel_launch(void* const* d_in, const int* in_sizes, int n_in,
                              void* d_out, int out_size, void* d_ws, size_t ws_size,
                              hipStream_t stream)
{
    const float* hidden  = (const float*)d_in[0];
    const float* W_in    = (const float*)d_in[1];
    const float* conv_w  = (const float*)d_in[2];
    const float* conv_b  = (const float*)d_in[3];
    const float* dt_bias = (const float*)d_in[4];
    const float* A_log   = (const float*)d_in[5];
    const float* Dv      = (const float*)d_in[6];
    const float* norm_w  = (const float*)d_in[7];
    const float* W_out   = (const float*)d_in[8];
    float* out = (float*)d_out;

    char* ws = (char*)d_ws;
    size_t o = 0;
    ushort_t* zb   = (ushort_t*)(ws + o); o += (size_t)NTOK * DI * 2;               // 33.6 MB
    ushort_t* xbcb = (ushort_t*)(ws + o); o += (size_t)NTOK * CD * 2;               // 37.7 MB
    float* S       = (float*)(ws + o);    o += (size_t)BSZ * NH * NCH * HD * DS * 4;// 67.1 MB
    ushort_t* xT   = (ushort_t*)(ws + o); o += (size_t)DI * NTOK * 2;               // 33.6 MB
    ushort_t* Bn   = (ushort_t*)(ws + o); o += (size_t)NTOK * DS * 2;               // 2.1 MB
    ushort_t* BT   = (ushort_t*)(ws + o); o += (size_t)DS * NTOK * 2;               // 2.1 MB
    ushort_t* Cn   = (ushort_t*)(ws + o); o += (size_t)NTOK * DS * 2;               // 2.1 MB
    ushort_t* hsb  = (ushort_t*)(ws + o); o += (size_t)BSZ * NH * NCH * HD * DS * 2;// 33.6 MB
    float* dtv     = (float*)(ws + o);    o += (size_t)NTOK * NH * 4;               // 1.05 MB
    float* ldA     = (float*)(ws + o);    o += (size_t)NTOK * NH * 4;               // 1.05 MB
    float* lcpb    = (float*)(ws + o);    o += (size_t)BSZ * NH * LEN * 4;          // 1.05 MB
    float* dtsb    = (float*)(ws + o);    o += (size_t)BSZ * NH * LEN * 4;          // 1.05 MB
    float* coefb   = (float*)(ws + o);    o += (size_t)BSZ * NH * LEN * 4;          // 1.05 MB
    float* csum    = (float*)(ws + o);    o += (size_t)BSZ * NH * NCH * 4;          // 8 KB
    // total ~217.6 MB
    // Aliases (dead-region reuse):
    ushort_t* Ah   = (ushort_t*)S;                                   // pre-phase1
    ushort_t* W1t  = (ushort_t*)((char*)S + (size_t)NTOK * DM * 2);  // pre-phase1
    ushort_t* ybuf = (ushort_t*)S;                                   // post-phase2 (S dead)
    ushort_t* Wot  = hsb;                                            // post-phase3 (hsb dead)
    ushort_t* ynb  = xbcb;                                           // post-conv (xbcb dead)

    // 1) bf16 conversions for GEMM1
    cvt_bf16<<<(NTOK * DM) / 1024, 256, 0, stream>>>(hidden, Ah);
    transpose_cvt<<<dim3(NPAD / 32, DM / 32), 256, 0, stream>>>(W_in, W1t, DM, DP, DP);
    // 2) GEMM1 split: z part and xBC part (both bf16 out)
    gemm_bf16<true><<<dim3(DI / 128, NTOK / 128), 256, 0, stream>>>(
        Ah, W1t, zb, DM, DM, DM, DI, DI);
    gemm_bf16<true><<<dim3(19, NTOK / 128), 256, 0, stream>>>(
        Ah, W1t + (size_t)DI * DM, xbcb, DM, DM, DM, CD, CD);
    // 3) conv + SiLU -> bf16 operand caches
    conv_silu_bf16<<<dim3(CD / 256, NRB), 256, 0, stream>>>(
        xbcb, conv_w, conv_b, xT, Bn, BT, Cn);
    // 4) dt in fp32, then hoisted per-chunk prefix scan
    dt_proc_fp32<<<NTOK / 8, 256, 0, stream>>>(hidden, W_in, dt_bias, A_log, dtv, ldA);
    scan_chunk<<<BSZ * NH * NCH, 64, 0, stream>>>(dtv, ldA, lcpb, dtsb, coefb, csum);
    // 5) chunk states (MFMA) — overwrites Ah/W1t alias region (dead)
    phase1_mfma<<<BSZ * NH * NCH, 256, 0, stream>>>(xT, BT, coefb, S);
    // 6) cross-chunk recurrence -> bf16 h_start
    phase2<<<BSZ * NH * 8, 256, 0, stream>>>(S, csum, hsb);
    // 7) per-chunk outputs (MFMA) -> bf16 y into dead-S alias
    phase3_mfma<<<BSZ * NH * NCH, 256, 0, stream>>>(
        xT, Bn, Cn, hsb, lcpb, dtsb, Dv, ybuf);
    // 8) gate + RMSNorm -> bf16 y_norm (into xbcb alias)
    gate_rms<<<NTOK, 256, 0, stream>>>(zb, ybuf, norm_w, ynb);
    // 9) W_out transpose (hsb dead), then out = y_norm @ W_out
    transpose_cvt<<<dim3(DM / 32, DI / 32), 256, 0, stream>>>(W_out, Wot, DI, DM, DM);
    gemm_bf16<false><<<dim3(DM / 128, NTOK / 128), 256, 0, stream>>>(
        ynb, Wot, out, DI, DI, DI, DM, DM);
}

// Round 7
// 539.731 us; speedup vs baseline: 1.4975x; 1.0700x over previous
//
#include <hip/hip_runtime.h>
#include <math.h>

#define BSZ 4
#define LEN 2048
#define DM 1024
#define DI 2048
#define HD 64      // HEADDIM (p)
#define NH 32      // NHEADS
#define DS 128     // D_STATE (n)
#define CD 2304    // CONV_DIM
#define DP 4384    // D_IN_PROJ
#define NTOK (BSZ*LEN)   // 8192
#define QCH 128          // chunk length
#define NCH (LEN/QCH)    // 16 chunks
#define TOFF (DP-NH)     // 4352: dt raw cols in W_in

#define CONV_R 64
#define NRB (NTOK/CONV_R)
#define NPAD 4480        // W_in columns padded to 35*128

typedef unsigned short ushort_t;
typedef __bf16 bf16x8 __attribute__((ext_vector_type(8)));
typedef ushort_t us8 __attribute__((ext_vector_type(8)));
typedef float f32x4 __attribute__((ext_vector_type(4)));

__device__ __forceinline__ ushort_t f2bf(float f) {
    unsigned u = __float_as_uint(f);
    unsigned r = (u + 0x7FFFu + ((u >> 16) & 1u)) >> 16;
    return (ushort_t)r;
}
__device__ __forceinline__ float bf2f(ushort_t u) {
    return __uint_as_float(((unsigned)u) << 16);
}
__device__ __forceinline__ bf16x8 us2bf(us8 v) {
    union { us8 u; bf16x8 b; } x; x.u = v; return x.b;
}

__device__ __forceinline__ void gl_lds16(const void* g, void* l) {
    __builtin_amdgcn_global_load_lds(
        (const __attribute__((address_space(1))) void*)g,
        (__attribute__((address_space(3))) void*)l, 16, 0, 0);
}

// ---------------------------------------------------------------------------
// fp32 -> bf16 elementwise (hidden). 4 elems/thread.
// ---------------------------------------------------------------------------
__global__ __launch_bounds__(256) void cvt_bf16(
    const float* __restrict__ A, ushort_t* __restrict__ Ab)
{
    size_t i = ((size_t)blockIdx.x * 256 + threadIdx.x) * 4;
    float4 v = *(const float4*)(A + i);
    ushort_t o[4] = { f2bf(v.x), f2bf(v.y), f2bf(v.z), f2bf(v.w) };
    *(uint2*)(Ab + i) = *(uint2*)o;
}

// ---------------------------------------------------------------------------
// W[k][n] fp32 (ld=ldw) -> Wt[n][k] bf16 (ld=K), zero-pad for n >= N.
// ---------------------------------------------------------------------------
__global__ __launch_bounds__(256) void transpose_cvt(
    const float* __restrict__ W, ushort_t* __restrict__ Wt,
    int K, int N, int ldw)
{
    __shared__ float T[32][33];
    const int n0 = blockIdx.x * 32;
    const int k0 = blockIdx.y * 32;
    const int tid = threadIdx.x;
    #pragma unroll
    for (int l = 0; l < 4; l++) {
        int idx = tid + l * 256;
        int ki = idx >> 5, nj = idx & 31;
        int n = n0 + nj;
        T[ki][nj] = (n < N) ? W[(size_t)(k0 + ki) * ldw + n] : 0.f;
    }
    __syncthreads();
    #pragma unroll
    for (int l = 0; l < 4; l++) {
        int idx = tid + l * 256;
        int nj = idx >> 5, ki = idx & 31;
        Wt[(size_t)(n0 + nj) * K + k0 + ki] = f2bf(T[ki][nj]);
    }
}

// ---------------------------------------------------------------------------
// bf16 MFMA GEMM (B^T form): C[m][n] = sum_k A[m][k] * Bt[n][k].
// 128x128 tile, BK=32, m97 structure. OB: bf16 output else fp32.
// ---------------------------------------------------------------------------
template <bool OB>
__global__ __launch_bounds__(256) void gemm_bf16(
    const ushort_t* __restrict__ A, const ushort_t* __restrict__ Bt,
    void* __restrict__ Cp, int K, int lda, int ldb, int ldc, int nmax)
{
    __shared__ __align__(16) ushort_t As[128 * 32];
    __shared__ __align__(16) ushort_t Bs[128 * 32];
    const int tid = threadIdx.x;
    const int n0 = blockIdx.x * 128;
    const int m0 = blockIdx.y * 128;
    const int lane = tid & 63;
    const int w = tid >> 6;
    const int wm = w >> 1, wn = w & 1;
    const int lm = lane & 15, quad = lane >> 4;

    const int srow = tid >> 2;
    const int skq = (tid & 3) * 8;
    const ushort_t* ga0 = A + (size_t)(m0 + srow) * lda + skq;
    const ushort_t* ga1 = A + (size_t)(m0 + 64 + srow) * lda + skq;
    const ushort_t* gb0 = Bt + (size_t)(n0 + srow) * ldb + skq;
    const ushort_t* gb1 = Bt + (size_t)(n0 + 64 + srow) * ldb + skq;
    ushort_t* la0 = &As[srow * 32 + skq];
    ushort_t* la1 = &As[(64 + srow) * 32 + skq];
    ushort_t* lb0 = &Bs[srow * 32 + skq];
    ushort_t* lb1 = &Bs[(64 + srow) * 32 + skq];

    f32x4 acc[4][4];
    #pragma unroll
    for (int i = 0; i < 4; i++)
        #pragma unroll
        for (int j = 0; j < 4; j++) acc[i][j] = (f32x4){0.f, 0.f, 0.f, 0.f};

    for (int k0 = 0; k0 < K; k0 += 32) {
        gl_lds16(ga0, la0);
        gl_lds16(ga1, la1);
        gl_lds16(gb0, lb0);
        gl_lds16(gb1, lb1);
        ga0 += 32; ga1 += 32; gb0 += 32; gb1 += 32;
        __syncthreads();
        bf16x8 af[4], bfr[4];
        #pragma unroll
        for (int i = 0; i < 4; i++)
            af[i] = *(const bf16x8*)&As[(wm * 64 + i * 16 + lm) * 32 + quad * 8];
        #pragma unroll
        for (int j = 0; j < 4; j++)
            bfr[j] = *(const bf16x8*)&Bs[(wn * 64 + j * 16 + lm) * 32 + quad * 8];
        #pragma unroll
        for (int i = 0; i < 4; i++)
            #pragma unroll
            for (int j = 0; j < 4; j++)
                acc[i][j] = __builtin_amdgcn_mfma_f32_16x16x32_bf16(af[i], bfr[j], acc[i][j], 0, 0, 0);
        __syncthreads();
    }

    #pragma unroll
    for (int i = 0; i < 4; i++) {
        int row = m0 + wm * 64 + i * 16 + quad * 4;
        #pragma unroll
        for (int j = 0; j < 4; j++) {
            int col = n0 + wn * 64 + j * 16 + lm;
            if (col < nmax) {
                #pragma unroll
                for (int r = 0; r < 4; r++) {
                    if (OB)
                        ((ushort_t*)Cp)[(size_t)(row + r) * ldc + col] = f2bf(acc[i][j][r]);
                    else
                        ((float*)Cp)[(size_t)(row + r) * ldc + col] = acc[i][j][r];
                }
            }
        }
    }
}

// ---------------------------------------------------------------------------
// Depthwise causal conv (w=4) + bias + SiLU -> bf16 operand caches.
// Reads the xBC slice of zxb (bf16, ld=NPAD). xT/BT transposed via LDS tile
// (16B stores over 8 consecutive rows); Bn/Cn direct coalesced.
// ---------------------------------------------------------------------------
__global__ __launch_bounds__(256) void conv_silu_bf16(
    const ushort_t* __restrict__ xbcb, const float* __restrict__ cw,
    const float* __restrict__ cb, ushort_t* __restrict__ xT,
    ushort_t* __restrict__ Bn, ushort_t* __restrict__ BT,
    ushort_t* __restrict__ Cn)
{
    __shared__ ushort_t Tl[256][68];
    const int tid = threadIdx.x;
    const int c = blockIdx.x * 256 + tid;
    const int rb = blockIdx.y;
    const int row0 = rb * CONV_R;
    const bool isBC = (blockIdx.x == 8);

    const float w0 = cw[c*4+0], w1 = cw[c*4+1], w2 = cw[c*4+2], w3 = cw[c*4+3];
    const float bias = cb[c];
    float h0 = 0.f, h1 = 0.f, h2 = 0.f;
    if ((row0 & (LEN - 1)) != 0) {
        h0 = bf2f(xbcb[(size_t)(row0 - 3) * NPAD + c]);
        h1 = bf2f(xbcb[(size_t)(row0 - 2) * NPAD + c]);
        h2 = bf2f(xbcb[(size_t)(row0 - 1) * NPAD + c]);
    }
    const ushort_t* p = xbcb + (size_t)row0 * NPAD + c;
    for (int r = 0; r < CONV_R; r++) {
        float xin = bf2f(*p);
        float a = bias + w0*h0 + w1*h1 + w2*h2 + w3*xin;
        ushort_t bv = f2bf(a / (1.f + __expf(-a)));
        Tl[tid][r] = bv;
        if (isBC) {
            int row = row0 + r;
            if (tid < DS) Bn[(size_t)row * DS + tid] = bv;
            else          Cn[(size_t)row * DS + (tid - DS)] = bv;
        }
        h0 = h1; h1 = h2; h2 = xin;
        p += NPAD;
    }
    __syncthreads();

    const int seg = tid & 7;
    const int clb = tid >> 3;
    if (!isBC) {
        #pragma unroll
        for (int pass = 0; pass < 8; pass++) {
            int cl = pass * 32 + clb;
            int cc = blockIdx.x * 256 + cl;
            us8 v;
            #pragma unroll
            for (int j = 0; j < 8; j++) v[j] = Tl[cl][seg * 8 + j];
            *(us8*)&xT[(size_t)cc * NTOK + row0 + seg * 8] = v;
        }
    } else {
        #pragma unroll
        for (int pass = 0; pass < 4; pass++) {
            int n = pass * 32 + clb;
            us8 v;
            #pragma unroll
            for (int j = 0; j < 8; j++) v[j] = Tl[n][seg * 8 + j];
            *(us8*)&BT[(size_t)n * NTOK + row0 + seg * 8] = v;
        }
    }
}

// ---------------------------------------------------------------------------
// Batched head-independent GEMM: Graw[bc][t][s] = sum_n C[t,n]*B[s,n].
// One block per (b,chunk); 64 blocks. fp32 output (weighted per-head later).
// ---------------------------------------------------------------------------
__global__ __launch_bounds__(256) void gct_gemm(
    const ushort_t* __restrict__ Bn, const ushort_t* __restrict__ Cn,
    float* __restrict__ Graw)
{
    const int bc = blockIdx.x;             // b*NCH + chunk
    const int chunk = bc % NCH;
    const int b = bc / NCH;
    const size_t rowbase = (size_t)b * LEN + (size_t)chunk * QCH;
    const int tid = threadIdx.x;
    const int w = tid >> 6, lane = tid & 63;
    const int lm = lane & 15, quad = lane >> 4;
    const int tw0 = w * 32;

    f32x4 acc[2][8];
    #pragma unroll
    for (int ti = 0; ti < 2; ti++)
        #pragma unroll
        for (int sj = 0; sj < 8; sj++) acc[ti][sj] = (f32x4){0.f, 0.f, 0.f, 0.f};

    #pragma unroll
    for (int ks = 0; ks < 4; ks++) {
        const int k0 = ks * 32 + quad * 8;
        bf16x8 a0 = *(const bf16x8*)&Cn[(rowbase + tw0 + lm) * DS + k0];
        bf16x8 a1 = *(const bf16x8*)&Cn[(rowbase + tw0 + 16 + lm) * DS + k0];
        #pragma unroll
        for (int sj = 0; sj < 8; sj++) {
            bf16x8 bb = *(const bf16x8*)&Bn[(rowbase + sj * 16 + lm) * DS + k0];
            acc[0][sj] = __builtin_amdgcn_mfma_f32_16x16x32_bf16(a0, bb, acc[0][sj], 0, 0, 0);
            acc[1][sj] = __builtin_amdgcn_mfma_f32_16x16x32_bf16(a1, bb, acc[1][sj], 0, 0, 0);
        }
    }
    float* G = Graw + (size_t)bc * (QCH * QCH);
    #pragma unroll
    for (int ti = 0; ti < 2; ti++)
        #pragma unroll
        for (int sj = 0; sj < 8; sj++)
            #pragma unroll
            for (int r = 0; r < 4; r++)
                G[(size_t)(tw0 + ti * 16 + quad * 4 + r) * QCH + sj * 16 + lm] = acc[ti][sj][r];
}

// ---------------------------------------------------------------------------
// dt in FULL fp32 straight from hidden @ W_in[:, TOFF:] (exp-amplified path).
// ---------------------------------------------------------------------------
__global__ __launch_bounds__(256) void dt_proc_fp32(
    const float* __restrict__ hidden, const float* __restrict__ W_in,
    const float* __restrict__ dt_bias, const float* __restrict__ A_log,
    float* __restrict__ dtv, float* __restrict__ ldA)
{
    const int h = threadIdx.x & 31;
    const int tt = threadIdx.x >> 5;
    const int t = blockIdx.x * 8 + tt;
    const float* hr = hidden + (size_t)t * DM;
    const float* wc = W_in + TOFF + h;
    float a0 = 0.f, a1 = 0.f, a2 = 0.f, a3 = 0.f;
    for (int k = 0; k < DM; k += 4) {
        a0 += hr[k+0] * wc[(size_t)(k+0) * DP];
        a1 += hr[k+1] * wc[(size_t)(k+1) * DP];
        a2 += hr[k+2] * wc[(size_t)(k+2) * DP];
        a3 += hr[k+3] * wc[(size_t)(k+3) * DP];
    }
    float v = (a0 + a1) + (a2 + a3) + dt_bias[h];
    float sp = (v > 20.f) ? v : log1pf(expf(v));
    int idx = t * NH + h;
    dtv[idx] = sp;
    ldA[idx] = -sp * expf(A_log[h]);
}

// ---------------------------------------------------------------------------
// Per-(b,h,chunk) prefix scan of ldA (one wave per block, shfl-based).
// ---------------------------------------------------------------------------
__global__ __launch_bounds__(64) void scan_chunk(
    const float* __restrict__ dtv, const float* __restrict__ ldA,
    float* __restrict__ lcpb, float* __restrict__ dtsb,
    float* __restrict__ coefb, float* __restrict__ csum)
{
    const int blk = blockIdx.x;            // bh*NCH + chunk
    const int chunk = blk % NCH;
    const int bh = blk / NCH;
    const int h = bh % NH;
    const int b = bh / NH;
    const int lane = threadIdx.x;
    const size_t rowbase = (size_t)b * LEN + (size_t)chunk * QCH;
    const int t0 = 2 * lane, t1 = 2 * lane + 1;
    float v0 = ldA[(rowbase + t0) * NH + h];
    float v1 = ldA[(rowbase + t1) * NH + h];
    float d0 = dtv[(rowbase + t0) * NH + h];
    float d1 = dtv[(rowbase + t1) * NH + h];
    float pair = v0 + v1;
    #pragma unroll
    for (int off = 1; off < 64; off <<= 1) {
        float n = __shfl_up(pair, off, 64);
        if (lane >= off) pair += n;
    }
    float l1 = pair, l0 = pair - v1;
    float total = __shfl(pair, 63, 64);
    size_t base = (size_t)blk * QCH;
    *(float2*)&lcpb[base + t0] = make_float2(l0, l1);
    *(float2*)&dtsb[base + t0] = make_float2(d0, d1);
    *(float2*)&coefb[base + t0] =
        make_float2(__expf(total - l0) * d0, __expf(total - l1) * d1);
    if (lane == 63) csum[blk] = total;
}

// ---------------------------------------------------------------------------
// Phase 1 (MFMA): per (b,h,chunk): S[p][n] = sum_s (coef_s*x[s,p]) * B[s,n].
// Grid is h-minor so the 32 blocks sharing BT are adjacent (L2 locality).
// ---------------------------------------------------------------------------
__global__ __launch_bounds__(256) void phase1_mfma(
    const ushort_t* __restrict__ xT, const ushort_t* __restrict__ BT,
    const float* __restrict__ coefb, float* __restrict__ S)
{
    const int h = blockIdx.x & (NH - 1);
    const int bc = blockIdx.x >> 5;        // b*NCH + chunk
    const int chunk = bc % NCH;
    const int b = bc / NCH;
    const int blko = (b * NH + h) * NCH + chunk;
    const int tid = threadIdx.x;
    const size_t rowbase = (size_t)b * LEN + (size_t)chunk * QCH;

    __shared__ float coef[QCH];
    if (tid < QCH) coef[tid] = coefb[(size_t)blko * QCH + tid];
    __syncthreads();

    const int w = tid >> 6, lane = tid & 63;
    const int lm = lane & 15, quad = lane >> 4;
    const int nw0 = w * 32;

    f32x4 acc[4][2];
    #pragma unroll
    for (int i = 0; i < 4; i++)
        #pragma unroll
        for (int j = 0; j < 2; j++) acc[i][j] = (f32x4){0.f, 0.f, 0.f, 0.f};

    #pragma unroll
    for (int ks = 0; ks < 4; ks++) {
        const int k0 = ks * 32 + quad * 8;
        bf16x8 a[4];
        #pragma unroll
        for (int mi = 0; mi < 4; mi++)
            a[mi] = *(const bf16x8*)&xT[(size_t)(h * HD + mi * 16 + lm) * NTOK + rowbase + k0];
        float cf[8];
        #pragma unroll
        for (int j = 0; j < 8; j++) cf[j] = coef[k0 + j];
        #pragma unroll
        for (int ni = 0; ni < 2; ni++) {
            us8 raw = *(const us8*)&BT[(size_t)(nw0 + ni * 16 + lm) * NTOK + rowbase + k0];
            us8 sb;
            #pragma unroll
            for (int j = 0; j < 8; j++) sb[j] = f2bf(bf2f(raw[j]) * cf[j]);
            bf16x8 bfr = us2bf(sb);
            #pragma unroll
            for (int mi = 0; mi < 4; mi++)
                acc[mi][ni] = __builtin_amdgcn_mfma_f32_16x16x32_bf16(a[mi], bfr, acc[mi][ni], 0, 0, 0);
        }
    }
    float* Sb = S + (size_t)blko * (HD * DS);
    #pragma unroll
    for (int mi = 0; mi < 4; mi++)
        #pragma unroll
        for (int ni = 0; ni < 2; ni++)
            #pragma unroll
            for (int r = 0; r < 4; r++)
                Sb[(size_t)(mi * 16 + quad * 4 + r) * DS + nw0 + ni * 16 + lm] = acc[mi][ni][r];
}

// ---------------------------------------------------------------------------
// Phase 2: cross-chunk recurrence. fp32 S -> bf16 h_start (hsb).
// ---------------------------------------------------------------------------
__global__ __launch_bounds__(256) void phase2(
    const float* __restrict__ S, const float* __restrict__ csum,
    ushort_t* __restrict__ hsb)
{
    const int bh = blockIdx.x >> 3;
    const int esl = blockIdx.x & 7;
    const int tid = threadIdx.x;
    const int eb = esl * 1024 + tid;
    float run[4] = {0.f, 0.f, 0.f, 0.f};
    for (int c = 0; c < NCH; c++) {
        float P = __expf(csum[bh * NCH + c]);
        size_t base = (size_t)(bh * NCH + c) * (HD * DS);
        #pragma unroll
        for (int i = 0; i < 4; i++) {
            size_t idx = base + eb + i * 256;
            float s = S[idx];
            hsb[idx] = f2bf(run[i]);
            run[i] = P * run[i] + s;
        }
    }
}

// ---------------------------------------------------------------------------
// Phase 3 (MFMA): per (b,h,chunk), h-minor grid. Reads head-shared Graw
// (fp32, L2-hot across the 32 h-blocks), weights it per-head in registers
// into the MFMA A-fragment directly (no LDS transpose, no Step-A GEMM), then
// one fused K=256 contraction: Y = G@X + Chat@hs^T. Epilogue adds D*x,
// writes bf16 y.
// ---------------------------------------------------------------------------
__global__ __launch_bounds__(256) void phase3_mfma(
    const ushort_t* __restrict__ xT, const ushort_t* __restrict__ Cn,
    const ushort_t* __restrict__ hsb, const float* __restrict__ Graw,
    const float* __restrict__ lcpb, const float* __restrict__ dtsb,
    const float* __restrict__ Dvec, ushort_t* __restrict__ ybuf)
{
    const int tid = threadIdx.x;
    const int h = blockIdx.x & (NH - 1);
    const int bc = blockIdx.x >> 5;        // b*NCH + chunk
    const int chunk = bc % NCH;
    const int b = bc / NCH;
    const int blko = (b * NH + h) * NCH + chunk;
    const size_t rowbase = (size_t)b * LEN + (size_t)chunk * QCH;

    __shared__ float lcp[QCH];
    __shared__ float dts[QCH];
    if (tid < QCH) {
        lcp[tid] = lcpb[(size_t)blko * QCH + tid];
        dts[tid] = dtsb[(size_t)blko * QCH + tid];
    }
    __syncthreads();

    const int w = tid >> 6, lane = tid & 63;
    const int lm = lane & 15, quad = lane >> 4;
    const int tw0 = w * 32;

    const float* Gr = Graw + (size_t)bc * (QCH * QCH);
    const ushort_t* hsp = hsb + (size_t)blko * (HD * DS);

    f32x4 acc2[2][4];
    #pragma unroll
    for (int ti = 0; ti < 2; ti++)
        #pragma unroll
        for (int pi = 0; pi < 4; pi++) acc2[ti][pi] = (f32x4){0.f, 0.f, 0.f, 0.f};

    #pragma unroll
    for (int ks = 0; ks < 8; ks++) {
        bf16x8 a[2], bb[4];
        if (ks < 4) {
            const int k0 = ks * 32 + quad * 8;
            #pragma unroll
            for (int ti = 0; ti < 2; ti++) {
                int t = tw0 + ti * 16 + lm;
                float lt = lcp[t];
                const float* gp = Gr + (size_t)t * QCH + k0;
                float4 g0 = *(const float4*)gp;
                float4 g1 = *(const float4*)(gp + 4);
                float ge[8] = { g0.x, g0.y, g0.z, g0.w, g1.x, g1.y, g1.z, g1.w };
                us8 sb;
                #pragma unroll
                for (int j = 0; j < 8; j++) {
                    int s = k0 + j;
                    float wv = (s <= t) ? (__expf(lt - lcp[s]) * dts[s]) : 0.f;
                    sb[j] = f2bf(ge[j] * wv);
                }
                a[ti] = us2bf(sb);
            }
            #pragma unroll
            for (int pi = 0; pi < 4; pi++)
                bb[pi] = *(const bf16x8*)&xT[(size_t)(h * HD + pi * 16 + lm) * NTOK + rowbase + k0];
        } else {
            const int k0 = (ks - 4) * 32 + quad * 8;
            #pragma unroll
            for (int ti = 0; ti < 2; ti++) {
                int t = tw0 + ti * 16 + lm;
                float sc = __expf(lcp[t]);
                us8 raw = *(const us8*)&Cn[(rowbase + t) * DS + k0];
                us8 sb;
                #pragma unroll
                for (int j = 0; j < 8; j++) sb[j] = f2bf(bf2f(raw[j]) * sc);
                a[ti] = us2bf(sb);
            }
            #pragma unroll
            for (int pi = 0; pi < 4; pi++)
                bb[pi] = *(const bf16x8*)&hsp[(size_t)(pi * 16 + lm) * DS + k0];
        }
        #pragma unroll
        for (int ti = 0; ti < 2; ti++)
            #pragma unroll
            for (int pi = 0; pi < 4; pi++)
                acc2[ti][pi] = __builtin_amdgcn_mfma_f32_16x16x32_bf16(a[ti], bb[pi], acc2[ti][pi], 0, 0, 0);
    }

    const float Dh = Dvec[h];
    ushort_t* yb = ybuf + (size_t)blko * (HD * QCH);   // [t][p]
    #pragma unroll
    for (int ti = 0; ti < 2; ti++)
        #pragma unroll
        for (int pi = 0; pi < 4; pi++) {
            int tb = tw0 + ti * 16 + quad * 4;
            ushort4 xv = *(const ushort4*)&xT[(size_t)(h * HD + pi * 16 + lm) * NTOK + rowbase + tb];
            const ushort_t* xe = (const ushort_t*)&xv;
            #pragma unroll
            for (int r = 0; r < 4; r++) {
                float y = acc2[ti][pi][r] + Dh * bf2f(xe[r]);
                yb[(size_t)(tb + r) * HD + pi * 16 + lm] = f2bf(y);
            }
        }
}

// ---------------------------------------------------------------------------
// Gate (y * silu(z)) + RMSNorm over DI. z from zxb's z slice (ld=NPAD);
// writes bf16 y_norm into zxb's dead xBC slice (cols DI.., ld=NPAD).
// ---------------------------------------------------------------------------
__global__ __launch_bounds__(256) void gate_rms(
    ushort_t* __restrict__ zxb, const ushort_t* __restrict__ ybuf,
    const float* __restrict__ nw)
{
    const int row = blockIdx.x;
    const int tid = threadIdx.x;
    const int b = row >> 11;
    const int l = row & (LEN - 1);
    const int chunk = l >> 7;
    const int t = l & (QCH - 1);
    ushort_t* zr = zxb + (size_t)row * NPAD;
    float g[8];
    float ss = 0.f;
    #pragma unroll
    for (int i = 0; i < 8; i++) {
        int c = tid + i * 256;
        int h = c >> 6;
        int p = c & 63;
        float y = bf2f(ybuf[((size_t)((b * NH + h) * NCH + chunk)) * (HD * QCH) + t * HD + p]);
        float z = bf2f(zr[c]);
        float sg = z / (1.f + __expf(-z));
        float v = y * sg;
        g[i] = v;
        ss += v * v;
    }
    #pragma unroll
    for (int off = 32; off > 0; off >>= 1) ss += __shfl_down(ss, off, 64);
    __shared__ float red[4];
    if ((tid & 63) == 0) red[tid >> 6] = ss;
    __syncthreads();
    float tot = red[0] + red[1] + red[2] + red[3];
    float r = rsqrtf(tot * (1.f / DI) + 1e-5f);
    #pragma unroll
    for (int i = 0; i < 8; i++) {
        int c = tid + i * 256;
        zr[DI + c] = f2bf(g[i] * r * nw[c]);
    }
}

// ---------------------------------------------------------------------------
extern "C" void kernel_launch(void* const* d_in, const int* in_sizes, int n_in,
                              void* d_out, int out_size, void* d_ws, size_t ws_size,
                              hipStream_t stream)
{
    const float* hidden  = (const float*)d_in[0];
    const float* W_in    = (const float*)d_in[1];
    const float* conv_w  = (const float*)d_in[2];
    const float* conv_b  = (const float*)d_in[3];
    const float* dt_bias = (const float*)d_in[4];
    const float* A_log   = (const float*)d_in[5];
    const float* Dv      = (const float*)d_in[6];
    const float* norm_w  = (const float*)d_in[7];
    const float* W_out   = (const float*)d_in[8];
    float* out = (float*)d_out;

    char* ws = (char*)d_ws;
    size_t o = 0;
    ushort_t* zxb  = (ushort_t*)(ws + o); o += (size_t)NTOK * NPAD * 2;             // 73.4 MB
    float* S       = (float*)(ws + o);    o += (size_t)BSZ * NH * NCH * HD * DS * 4;// 67.1 MB
    ushort_t* xT   = (ushort_t*)(ws + o); o += (size_t)DI * NTOK * 2;               // 33.6 MB
    ushort_t* Bn   = (ushort_t*)(ws + o); o += (size_t)NTOK * DS * 2;               // 2.1 MB
    ushort_t* BT   = (ushort_t*)(ws + o); o += (size_t)DS * NTOK * 2;               // 2.1 MB
    ushort_t* Cn   = (ushort_t*)(ws + o); o += (size_t)NTOK * DS * 2;               // 2.1 MB
    ushort_t* hsb  = (ushort_t*)(ws + o); o += (size_t)BSZ * NH * NCH * HD * DS * 2;// 33.6 MB
    float* Graw    = (float*)(ws + o);    o += (size_t)BSZ * NCH * QCH * QCH * 4;   // 4.2 MB
    float* dtv     = (float*)(ws + o);    o += (size_t)NTOK * NH * 4;
    float* ldA     = (float*)(ws + o);    o += (size_t)NTOK * NH * 4;
    float* lcpb    = (float*)(ws + o);    o += (size_t)BSZ * NH * LEN * 4;
    float* dtsb    = (float*)(ws + o);    o += (size_t)BSZ * NH * LEN * 4;
    float* coefb   = (float*)(ws + o);    o += (size_t)BSZ * NH * LEN * 4;
    float* csum    = (float*)(ws + o);    o += (size_t)BSZ * NH * NCH * 4;
    // total ~223.6 MB
    // Aliases (dead-region reuse):
    ushort_t* Ah   = (ushort_t*)S;                                   // pre-phase1
    ushort_t* W1t  = (ushort_t*)((char*)S + (size_t)NTOK * DM * 2);  // pre-phase1
    ushort_t* ybuf = (ushort_t*)S;                                   // post-phase2 (S dead)
    ushort_t* Wot  = hsb;                                            // post-phase3 (hsb dead)
    ushort_t* xbcb = zxb + DI;                                       // xBC slice, ld=NPAD
    ushort_t* ynb  = zxb + DI;                                       // y_norm slice (post-conv), ld=NPAD

    // 1) bf16 conversions for GEMM1
    cvt_bf16<<<(NTOK * DM) / 1024, 256, 0, stream>>>(hidden, Ah);
    transpose_cvt<<<dim3(NPAD / 32, DM / 32), 256, 0, stream>>>(W_in, W1t, DM, DP, DP);
    // 2) GEMM1 (merged z + xBC, bf16 out)
    gemm_bf16<true><<<dim3(NPAD / 128, NTOK / 128), 256, 0, stream>>>(
        Ah, W1t, zxb, DM, DM, DM, NPAD, NPAD);
    // 3) conv + SiLU -> bf16 operand caches
    conv_silu_bf16<<<dim3(CD / 256, NRB), 256, 0, stream>>>(
        xbcb, conv_w, conv_b, xT, Bn, BT, Cn);
    // 4) head-shared C.B^T (once per (b,chunk))
    gct_gemm<<<BSZ * NCH, 256, 0, stream>>>(Bn, Cn, Graw);
    // 5) dt in fp32 + hoisted per-chunk prefix scan
    dt_proc_fp32<<<NTOK / 8, 256, 0, stream>>>(hidden, W_in, dt_bias, A_log, dtv, ldA);
    scan_chunk<<<BSZ * NH * NCH, 64, 0, stream>>>(dtv, ldA, lcpb, dtsb, coefb, csum);
    // 6) chunk states (MFMA, h-minor grid) — overwrites Ah/W1t alias (dead)
    phase1_mfma<<<BSZ * NH * NCH, 256, 0, stream>>>(xT, BT, coefb, S);
    // 7) cross-chunk recurrence -> bf16 h_start
    phase2<<<BSZ * NH * 8, 256, 0, stream>>>(S, csum, hsb);
    // 8) per-chunk outputs (MFMA, h-minor, Graw-based) -> bf16 y into dead-S
    phase3_mfma<<<BSZ * NH * NCH, 256, 0, stream>>>(
        xT, Cn, hsb, Graw, lcpb, dtsb, Dv, ybuf);
    // 9) gate + RMSNorm -> bf16 y_norm into zxb's dead xBC slice
    gate_rms<<<NTOK, 256, 0, stream>>>(zxb, ybuf, norm_w);
    // 10) W_out transpose (hsb dead), then out = y_norm @ W_out
    transpose_cvt<<<dim3(DM / 32, DI / 32), 256, 0, stream>>>(W_out, Wot, DI, DM, DM);
    gemm_bf16<false><<<dim3(DM / 128, NTOK / 128), 256, 0, stream>>>(
        ynb, Wot, out, DI, NPAD, DI, DM, DM);
}